// Round 1
// 295.222 us; speedup vs baseline: 1.4334x; 1.4334x over previous
//
#include <hip/hip_runtime.h>
#include <math.h>

#define LPTS 257
#define NPIX 65536
#define PPB  32      // pixels per block in the CDF kernel

// ===========================================================================
// XLA-CPU float32 emulation (unchanged from the verified round-12 kernel):
//   exp  : Eigen pexp (fmaf)
//   erf  : XLA alpha/beta rational, fmaf
//   einsum: fused fmaf chain
//   t    : f64 linspace/255 rounded to f32
//   cast : XLA float->int16 SATURATES high; int16 ADD wraps.
// This round is a pure RESTRUCTURING for occupancy: all float arithmetic is
// bit-identical to the previous (passing, absmax=128) kernel.
// ===========================================================================

__device__ __forceinline__ float xla_exp32(float x)
{
#pragma clang fp contract(off)
    x = fminf(x, 88.3762626647950f);
    x = fmaxf(x, -87.3365478515625f);
    const float m = floorf(fmaf(x, 1.44269504088896341f, 0.5f));
    float r = fmaf(m, -0.693359375f, x);
    r = fmaf(m, 2.12194440e-4f, r);
    const float r2 = r * r;
    float p = 1.9875691500e-4f;
    p = fmaf(p, r, 1.3981999507e-3f);
    p = fmaf(p, r, 8.3334519073e-3f);
    p = fmaf(p, r, 4.1665795894e-2f);
    p = fmaf(p, r, 1.6666665459e-1f);
    p = fmaf(p, r, 5.0000001201e-1f);
    float y = fmaf(p, r2, r) + 1.0f;
    const int e = (int)m;
    const float s = __int_as_float((e + 127) << 23);   // 2^m
    return y * s;
}

__device__ __forceinline__ float xla_erf32(float x)
{
#pragma clang fp contract(off)
    x = fminf(fmaxf(x, -4.0f), 4.0f);
    const float x2 = x * x;
    float pa = -2.72614225801306e-10f;
    pa = fmaf(pa, x2, 2.77068142495902e-08f);
    pa = fmaf(pa, x2, -2.10102402082508e-06f);
    pa = fmaf(pa, x2, -5.69250639462346e-05f);
    pa = fmaf(pa, x2, -7.34990630326855e-04f);
    pa = fmaf(pa, x2, -2.95459980854025e-03f);
    pa = fmaf(pa, x2, -1.60960333262415e-02f);
    float pb = -1.45660718464996e-05f;
    pb = fmaf(pb, x2, -2.13374055278905e-04f);
    pb = fmaf(pb, x2, -1.68282697438203e-03f);
    pb = fmaf(pb, x2, -7.37332916720468e-03f);
    pb = fmaf(pb, x2, -1.42647390514189e-02f);
    return x * pa / pb;
}

// erfc core for x >= 1
__device__ __forceinline__ float xla_erfc_ge1(float x)
{
#pragma clang fp contract(off)
    const float z = xla_exp32(-(x * x));
    const float q = 1.0f / x;
    const float y2 = q * q;
    float p;
    if (x < 2.0f) {
        p = 2.326819970068386e-02f;
        p = fmaf(p, y2, -1.387039388740657e-01f);
        p = fmaf(p, y2, 3.687424674597105e-01f);
        p = fmaf(p, y2, -5.824733027278666e-01f);
        p = fmaf(p, y2, 6.210004621745983e-01f);
        p = fmaf(p, y2, -4.944515323274145e-01f);
        p = fmaf(p, y2, 3.404879937665872e-01f);
        p = fmaf(p, y2, -2.741127028184656e-01f);
        p = fmaf(p, y2, 5.638259427386472e-01f);
    } else {
        p = -1.047766399936249e+01f;
        p = fmaf(p, y2, 1.297719955372516e+01f);
        p = fmaf(p, y2, -7.495518717768503e+00f);
        p = fmaf(p, y2, 2.921019019210786e+00f);
        p = fmaf(p, y2, -1.015265279202700e+00f);
        p = fmaf(p, y2, 4.218463358204948e-01f);
        p = fmaf(p, y2, -2.820767439740514e-01f);
        p = fmaf(p, y2, 5.641895067754075e-01f);
    }
    return z * q * p;
}

__device__ __forceinline__ float xla_ndtr32(float zf)
{
#pragma clang fp contract(off)
    const float c = __uint_as_float(0x3f3504f3u);   // f32(0.5*f32(sqrt(2)))
    const float w = zf * c;
    const float aw = fabsf(w);
    float y;
    if (aw < c) {
        y = 1.0f + xla_erf32(w);
    } else {
        const float e = (aw > 1.0f) ? xla_erfc_ge1(aw)
                                    : (1.0f - xla_erf32(aw));
        y = (w > 0.0f) ? (2.0f - e) : e;
    }
    return 0.5f * y;
}

// saturating f32->i16 cast (XLA semantics), then wrapping i16 add of l
__device__ __forceinline__ int quantize(float cdf, int l)
{
    int r = (int)rintf(cdf * 65280.0f);
    r = r > 32767 ? 32767 : r;
    r = r < -32768 ? -32768 : r;
    return (int)((short)(r + l));
}

// ===========================================================================
// Kernel A: CNN -> per-pixel mixture params.  Grid (256 tiles, 3 groups).
// Group g of the grouped convs produces exactly one param type:
//   g=0 -> mu[3], g=1 -> scale[3], g=2 -> softmax weights[3].
// Stores SoA prm_g[j*NPIX + pix], j in 0..8.
// ===========================================================================
__global__ __launch_bounds__(256) void entropy_params(
    const float* __restrict__ y,
    const float* __restrict__ W0, const float* __restrict__ b0,
    const float* __restrict__ W1, const float* __restrict__ b1,
    const float* __restrict__ W2, const float* __restrict__ b2,
    float* __restrict__ prm_g)
{
#pragma clang fp contract(off)
    __shared__ float tile[21][22];

    const int bx  = blockIdx.x & 15;
    const int by  = blockIdx.x >> 4;
    const int g   = blockIdx.y;
    const int tid = threadIdx.x;
    const int tx  = tid & 15;
    const int ty  = tid >> 4;

    for (int idx = tid; idx < 21 * 21; idx += 256) {
        const int r = idx / 21;
        const int c = idx - r * 21;
        int gy = by * 16 - 2 + r; gy = gy < 0 ? 0 : (gy > 255 ? 255 : gy);
        int gx = bx * 16 - 2 + c; gx = gx < 0 ? 0 : (gx > 255 ? 255 : gx);
        tile[r][c] = y[gy * 256 + gx];
    }
    __syncthreads();

    float patch[36];
#pragma unroll
    for (int i = 0; i < 6; ++i)
#pragma unroll
        for (int j = 0; j < 6; ++j)
            patch[i * 6 + j] = tile[ty + i][tx + j];

    float h0[64];
#pragma unroll 2
    for (int c = 0; c < 64; ++c) {
        float acc = 0.0f;
        const float* w = W0 + (g * 64 + c) * 36;
#pragma unroll
        for (int k = 0; k < 36; ++k)
            acc = fmaf(w[k], patch[k], acc);
        acc = acc + b0[g * 64 + c];
        h0[c] = fmaxf(acc, 0.0f);
    }

    float p0 = 0.0f, p1 = 0.0f, p2 = 0.0f;
#pragma unroll 2
    for (int c = 0; c < 64; ++c) {
        float acc = 0.0f;
        const float* w = W1 + (g * 64 + c) * 64;
#pragma unroll
        for (int j = 0; j < 64; ++j)
            acc = fmaf(w[j], h0[j], acc);
        acc = acc + b1[g * 64 + c];
        acc = fmaxf(acc, 0.0f);
        p0 = fmaf(W2[(3 * g + 0) * 64 + c], acc, p0);
        p1 = fmaf(W2[(3 * g + 1) * 64 + c], acc, p1);
        p2 = fmaf(W2[(3 * g + 2) * 64 + c], acc, p2);
    }
    p0 = p0 + b2[3 * g + 0];
    p1 = p1 + b2[3 * g + 1];
    p2 = p2 + b2[3 * g + 2];

    const int pix = (by * 16 + ty) * 256 + bx * 16 + tx;

    if (g == 0) {
        prm_g[0 * NPIX + pix] = p0;
        prm_g[1 * NPIX + pix] = p1;
        prm_g[2 * NPIX + pix] = p2;
    } else if (g == 1) {
        prm_g[3 * NPIX + pix] = fmaxf(xla_exp32(p0), 0.11f);
        prm_g[4 * NPIX + pix] = fmaxf(xla_exp32(p1), 0.11f);
        prm_g[5 * NPIX + pix] = fmaxf(xla_exp32(p2), 0.11f);
    } else {
        const float m  = fmaxf(fmaxf(p0, p1), p2);
        const float e0 = xla_exp32(p0 - m);
        const float e1 = xla_exp32(p1 - m);
        const float e2 = xla_exp32(p2 - m);
        const float s  = (e0 + e1) + e2;
        prm_g[6 * NPIX + pix] = e0 / s;
        prm_g[7 * NPIX + pix] = e1 / s;
        prm_g[8 * NPIX + pix] = e2 / s;
    }
}

// ===========================================================================
// Kernel B: CDF evaluation.  Grid NPIX/PPB = 2048 blocks, 256 threads.
// Thread tid evaluates point l = tid for PPB pixels (coalesced stores),
// then threads 0..PPB-1 handle the l=256 tail point.
// ===========================================================================
__global__ __launch_bounds__(256) void entropy_cdf(
    const float* __restrict__ prm_g,
    int* __restrict__ out)
{
#pragma clang fp contract(off)
    __shared__ float prm[9][PPB];

    const int base = blockIdx.x * PPB;
    const int tid  = threadIdx.x;

    for (int i = tid; i < 9 * PPB; i += 256)
        prm[i >> 5][i & 31] = prm_g[(i >> 5) * NPIX + base + (i & 31)];
    __syncthreads();

    const float CLIP = (float)(1.0 - 1e-6);

    // main: point l = tid for every pixel in the block
    {
        const int l = tid;
        const float t32 = (l == 0)
            ? (float)(-147.5 / 255.0)
            : (float)((((double)l) - 127.5) / 255.0);
#pragma unroll 2
        for (int p = 0; p < PPB; ++p) {
            const float mu0 = prm[0][p], mu1 = prm[1][p], mu2 = prm[2][p];
            const float sc0 = prm[3][p], sc1 = prm[4][p], sc2 = prm[5][p];
            const float w0  = prm[6][p], w1  = prm[7][p], w2  = prm[8][p];

            const float n0 = xla_ndtr32((t32 - mu0) / sc0);
            const float n1 = xla_ndtr32((t32 - mu1) / sc1);
            const float n2 = xla_ndtr32((t32 - mu2) / sc2);

            float cdf = fmaf(w2, n2, fmaf(w1, n1, w0 * n0));
            cdf = fminf(fmaxf(cdf, 0.0f), CLIP);

            out[(size_t)(base + p) * LPTS + l] = quantize(cdf, l);
        }
    }

    // tail: point l = 256, one pixel per thread
    if (tid < PPB) {
        const int p = tid;
        const float t32 = (float)(148.5 / 255.0);
        const float mu0 = prm[0][p], mu1 = prm[1][p], mu2 = prm[2][p];
        const float sc0 = prm[3][p], sc1 = prm[4][p], sc2 = prm[5][p];
        const float w0  = prm[6][p], w1  = prm[7][p], w2  = prm[8][p];

        const float n0 = xla_ndtr32((t32 - mu0) / sc0);
        const float n1 = xla_ndtr32((t32 - mu1) / sc1);
        const float n2 = xla_ndtr32((t32 - mu2) / sc2);

        float cdf = fmaf(w2, n2, fmaf(w1, n1, w0 * n0));
        cdf = fminf(fmaxf(cdf, 0.0f), CLIP);

        out[(size_t)(base + p) * LPTS + 256] = quantize(cdf, 256);
    }
}

// ===========================================================================
// Fallback: previous fused single-kernel (used only if ws_size is too small).
// ===========================================================================
__global__ __launch_bounds__(256) void entropy_fused(
    const float* __restrict__ y,
    const float* __restrict__ W0, const float* __restrict__ b0,
    const float* __restrict__ W1, const float* __restrict__ b1,
    const float* __restrict__ W2, const float* __restrict__ b2,
    int* __restrict__ out)
{
#pragma clang fp contract(off)

    __shared__ float tile[21][22];
    __shared__ float prm[9][257];

    const int bx  = blockIdx.x & 15;
    const int by  = blockIdx.x >> 4;
    const int tid = threadIdx.x;
    const int tx  = tid & 15;
    const int ty  = tid >> 4;

    for (int idx = tid; idx < 21 * 21; idx += 256) {
        const int r = idx / 21;
        const int c = idx - r * 21;
        int gy = by * 16 - 2 + r; gy = gy < 0 ? 0 : (gy > 255 ? 255 : gy);
        int gx = bx * 16 - 2 + c; gx = gx < 0 ? 0 : (gx > 255 ? 255 : gx);
        tile[r][c] = y[gy * 256 + gx];
    }
    __syncthreads();

    float patch[36];
#pragma unroll
    for (int i = 0; i < 6; ++i)
#pragma unroll
        for (int j = 0; j < 6; ++j)
            patch[i * 6 + j] = tile[ty + i][tx + j];

    for (int g = 0; g < 3; ++g) {
        float h0[64];
#pragma unroll 2
        for (int c = 0; c < 64; ++c) {
            float acc = 0.0f;
            const float* w = W0 + (g * 64 + c) * 36;
#pragma unroll
            for (int k = 0; k < 36; ++k)
                acc = fmaf(w[k], patch[k], acc);
            acc = acc + b0[g * 64 + c];
            h0[c] = fmaxf(acc, 0.0f);
        }

        float p0 = 0.0f, p1 = 0.0f, p2 = 0.0f;
#pragma unroll 2
        for (int c = 0; c < 64; ++c) {
            float acc = 0.0f;
            const float* w = W1 + (g * 64 + c) * 64;
#pragma unroll
            for (int j = 0; j < 64; ++j)
                acc = fmaf(w[j], h0[j], acc);
            acc = acc + b1[g * 64 + c];
            acc = fmaxf(acc, 0.0f);
            p0 = fmaf(W2[(3 * g + 0) * 64 + c], acc, p0);
            p1 = fmaf(W2[(3 * g + 1) * 64 + c], acc, p1);
            p2 = fmaf(W2[(3 * g + 2) * 64 + c], acc, p2);
        }
        p0 = p0 + b2[3 * g + 0];
        p1 = p1 + b2[3 * g + 1];
        p2 = p2 + b2[3 * g + 2];

        if (g == 0) {
            prm[0][tid] = p0; prm[1][tid] = p1; prm[2][tid] = p2;
        } else if (g == 1) {
            prm[3][tid] = fmaxf(xla_exp32(p0), 0.11f);
            prm[4][tid] = fmaxf(xla_exp32(p1), 0.11f);
            prm[5][tid] = fmaxf(xla_exp32(p2), 0.11f);
        } else {
            const float m  = fmaxf(fmaxf(p0, p1), p2);
            const float e0 = xla_exp32(p0 - m);
            const float e1 = xla_exp32(p1 - m);
            const float e2 = xla_exp32(p2 - m);
            const float s  = (e0 + e1) + e2;
            prm[6][tid] = e0 / s;
            prm[7][tid] = e1 / s;
            prm[8][tid] = e2 / s;
        }
    }
    __syncthreads();

    const int rowbase = (by * 16) * 256 + bx * 16;
    const float CLIP = (float)(1.0 - 1e-6);

    {
        const int l = tid;
        const float t32 = (l == 0)
            ? (float)(-147.5 / 255.0)
            : (float)((((double)l) - 127.5) / 255.0);
        for (int p = 0; p < 256; ++p) {
            const float mu0 = prm[0][p], mu1 = prm[1][p], mu2 = prm[2][p];
            const float sc0 = prm[3][p], sc1 = prm[4][p], sc2 = prm[5][p];
            const float w0  = prm[6][p], w1  = prm[7][p], w2  = prm[8][p];

            const float n0 = xla_ndtr32((t32 - mu0) / sc0);
            const float n1 = xla_ndtr32((t32 - mu1) / sc1);
            const float n2 = xla_ndtr32((t32 - mu2) / sc2);

            float cdf = fmaf(w2, n2, fmaf(w1, n1, w0 * n0));
            cdf = fminf(fmaxf(cdf, 0.0f), CLIP);

            const int pix = rowbase + (p >> 4) * 256 + (p & 15);
            out[(size_t)pix * LPTS + l] = quantize(cdf, l);
        }
    }

    {
        const int p = tid;
        const float t32 = (float)(148.5 / 255.0);
        const float mu0 = prm[0][p], mu1 = prm[1][p], mu2 = prm[2][p];
        const float sc0 = prm[3][p], sc1 = prm[4][p], sc2 = prm[5][p];
        const float w0  = prm[6][p], w1  = prm[7][p], w2  = prm[8][p];

        const float n0 = xla_ndtr32((t32 - mu0) / sc0);
        const float n1 = xla_ndtr32((t32 - mu1) / sc1);
        const float n2 = xla_ndtr32((t32 - mu2) / sc2);

        float cdf = fmaf(w2, n2, fmaf(w1, n1, w0 * n0));
        cdf = fminf(fmaxf(cdf, 0.0f), CLIP);

        const int pix = rowbase + (p >> 4) * 256 + (p & 15);
        out[(size_t)pix * LPTS + 256] = quantize(cdf, 256);
    }
}

// ===========================================================================
extern "C" void kernel_launch(void* const* d_in, const int* in_sizes, int n_in,
                              void* d_out, int out_size, void* d_ws, size_t ws_size,
                              hipStream_t stream)
{
    const float* y  = (const float*)d_in[0];
    const float* W0 = (const float*)d_in[1];
    const float* b0 = (const float*)d_in[2];
    const float* W1 = (const float*)d_in[3];
    const float* b1 = (const float*)d_in[4];
    const float* W2 = (const float*)d_in[5];
    const float* b2 = (const float*)d_in[6];

    int* out = (int*)d_out;   // 65536 * 257 int32

    const size_t need = (size_t)9 * NPIX * sizeof(float);
    if (d_ws != nullptr && ws_size >= need) {
        float* prm_g = (float*)d_ws;
        entropy_params<<<dim3(256, 3), dim3(256), 0, stream>>>(
            y, W0, b0, W1, b1, W2, b2, prm_g);
        entropy_cdf<<<dim3(NPIX / PPB), dim3(256), 0, stream>>>(prm_g, out);
    } else {
        entropy_fused<<<dim3(256), dim3(256), 0, stream>>>(
            y, W0, b0, W1, b1, W2, b2, out);
    }
}

// Round 2
// 202.432 us; speedup vs baseline: 2.0905x; 1.4584x over previous
//
#include <hip/hip_runtime.h>
#include <math.h>

#define LPTS 257
#define NPIX 65536
#define PPB  32      // pixels per block in the CDF kernel

// ===========================================================================
// XLA-CPU float32 emulation (bit-identical to the verified kernel):
//   exp  : Eigen pexp (fmaf)
//   erf  : XLA alpha/beta rational, fmaf
//   einsum: fused fmaf chain
//   t    : f64 linspace/255 rounded to f32
//   cast : XLA float->int16 SATURATES high; int16 ADD wraps.
// Round 14: ndtr restructured to compute erf ONCE (exploiting exact oddness
// of the XLA erf polynomial: erf(|w|) == |erf(w)| bitwise) and to hide the
// erfc path behind a wave-uniform ballot guard.  CNN weights staged in LDS
// as float4.  All float results bit-identical to the passing kernel.
// ===========================================================================

__device__ __forceinline__ float xla_exp32(float x)
{
#pragma clang fp contract(off)
    x = fminf(x, 88.3762626647950f);
    x = fmaxf(x, -87.3365478515625f);
    const float m = floorf(fmaf(x, 1.44269504088896341f, 0.5f));
    float r = fmaf(m, -0.693359375f, x);
    r = fmaf(m, 2.12194440e-4f, r);
    const float r2 = r * r;
    float p = 1.9875691500e-4f;
    p = fmaf(p, r, 1.3981999507e-3f);
    p = fmaf(p, r, 8.3334519073e-3f);
    p = fmaf(p, r, 4.1665795894e-2f);
    p = fmaf(p, r, 1.6666665459e-1f);
    p = fmaf(p, r, 5.0000001201e-1f);
    float y = fmaf(p, r2, r) + 1.0f;
    const int e = (int)m;
    const float s = __int_as_float((e + 127) << 23);   // 2^m
    return y * s;
}

__device__ __forceinline__ float xla_erf32(float x)
{
#pragma clang fp contract(off)
    x = fminf(fmaxf(x, -4.0f), 4.0f);
    const float x2 = x * x;
    float pa = -2.72614225801306e-10f;
    pa = fmaf(pa, x2, 2.77068142495902e-08f);
    pa = fmaf(pa, x2, -2.10102402082508e-06f);
    pa = fmaf(pa, x2, -5.69250639462346e-05f);
    pa = fmaf(pa, x2, -7.34990630326855e-04f);
    pa = fmaf(pa, x2, -2.95459980854025e-03f);
    pa = fmaf(pa, x2, -1.60960333262415e-02f);
    float pb = -1.45660718464996e-05f;
    pb = fmaf(pb, x2, -2.13374055278905e-04f);
    pb = fmaf(pb, x2, -1.68282697438203e-03f);
    pb = fmaf(pb, x2, -7.37332916720468e-03f);
    pb = fmaf(pb, x2, -1.42647390514189e-02f);
    return x * pa / pb;
}

// erfc core for x >= 1 (rare path)
__device__ __forceinline__ float xla_erfc_ge1(float x)
{
#pragma clang fp contract(off)
    const float z = xla_exp32(-(x * x));
    const float q = 1.0f / x;
    const float y2 = q * q;
    float p;
    if (x < 2.0f) {
        p = 2.326819970068386e-02f;
        p = fmaf(p, y2, -1.387039388740657e-01f);
        p = fmaf(p, y2, 3.687424674597105e-01f);
        p = fmaf(p, y2, -5.824733027278666e-01f);
        p = fmaf(p, y2, 6.210004621745983e-01f);
        p = fmaf(p, y2, -4.944515323274145e-01f);
        p = fmaf(p, y2, 3.404879937665872e-01f);
        p = fmaf(p, y2, -2.741127028184656e-01f);
        p = fmaf(p, y2, 5.638259427386472e-01f);
    } else {
        p = -1.047766399936249e+01f;
        p = fmaf(p, y2, 1.297719955372516e+01f);
        p = fmaf(p, y2, -7.495518717768503e+00f);
        p = fmaf(p, y2, 2.921019019210786e+00f);
        p = fmaf(p, y2, -1.015265279202700e+00f);
        p = fmaf(p, y2, 4.218463358204948e-01f);
        p = fmaf(p, y2, -2.820767439740514e-01f);
        p = fmaf(p, y2, 5.641895067754075e-01f);
    }
    return z * q * p;
}

// ndtr, restructured for the hot path.
// Bit-exactness vs the original 3-region form:
//  - aw <  c : y = 1 + erf(w)                       (same expression)
//  - c<=aw<=1: y = sel(w>0, 2-e, e), e = 1-erf(aw).
//              erf(aw) == fabsf(erf(w)) BITWISE: the clamp, x*x, the
//              polynomials (even in x), the final mul and div are all
//              exactly sign-symmetric, so erf is exactly odd.
//  - aw >  1 : identical erfc path, entered only when some lane needs it
//              (wave-uniform ballot => s_cbranch skip when none do).
__device__ __forceinline__ float xla_ndtr32(float zf)
{
#pragma clang fp contract(off)
    const float c = __uint_as_float(0x3f3504f3u);   // f32(0.5*f32(sqrt(2)))
    const float w = zf * c;
    const float aw = fabsf(w);

    const float E = xla_erf32(w);                   // exactly odd
    const float e_mid = 1.0f - fabsf(E);            // == 1 - erf(aw) bitwise
    float y = (aw < c) ? (1.0f + E)
                       : ((w > 0.0f) ? (2.0f - e_mid) : e_mid);

    if (__builtin_expect(__ballot(aw > 1.0f) != 0ull, 0)) {
        const float ec = xla_erfc_ge1(aw);          // garbage for aw<=1, unused
        const float yc = (w > 0.0f) ? (2.0f - ec) : ec;
        y = (aw > 1.0f) ? yc : y;
    }
    return 0.5f * y;
}

// saturating f32->i16 cast (XLA semantics), then wrapping i16 add of l
__device__ __forceinline__ int quantize(float cdf, int l)
{
    int r = (int)rintf(cdf * 65280.0f);
    r = r > 32767 ? 32767 : r;
    r = r < -32768 ? -32768 : r;
    return (int)((short)(r + l));
}

// ===========================================================================
// Kernel A: CNN -> per-pixel mixture params.  Grid (256 tiles, 3 groups).
// Weights for the block's group staged in LDS as float4; serial fmaf order
// per channel preserved exactly.
// ===========================================================================
__global__ __launch_bounds__(256) void entropy_params(
    const float* __restrict__ y,
    const float* __restrict__ W0, const float* __restrict__ b0,
    const float* __restrict__ W1, const float* __restrict__ b1,
    const float* __restrict__ W2, const float* __restrict__ b2,
    float* __restrict__ prm_g)
{
#pragma clang fp contract(off)
    __shared__ float tile[21][22];
    __shared__ __align__(16) float w0s[64 * 36];   //  9216 B
    __shared__ __align__(16) float w1s[64 * 64];   // 16384 B
    __shared__ __align__(16) float w2s[3 * 64];    //   768 B
    __shared__ __align__(16) float b0s[64];
    __shared__ __align__(16) float b1s[64];
    __shared__ float b2s[3];

    const int bx  = blockIdx.x & 15;
    const int by  = blockIdx.x >> 4;
    const int g   = blockIdx.y;
    const int tid = threadIdx.x;
    const int tx  = tid & 15;
    const int ty  = tid >> 4;

    // ---- stage weights (group slice) into LDS, coalesced float4 ----
    {
        const float4* src = (const float4*)(W0 + g * 64 * 36);   // 576 f4
        for (int i = tid; i < 576; i += 256) ((float4*)w0s)[i] = src[i];
    }
    {
        const float4* src = (const float4*)(W1 + g * 64 * 64);   // 1024 f4
        for (int i = tid; i < 1024; i += 256) ((float4*)w1s)[i] = src[i];
    }
    {
        const float4* src = (const float4*)(W2 + g * 3 * 64);    // 48 f4
        if (tid < 48) ((float4*)w2s)[tid] = src[tid];
    }
    {
        const float4* s0 = (const float4*)(b0 + g * 64);         // 16 f4
        const float4* s1 = (const float4*)(b1 + g * 64);
        if (tid < 16)      ((float4*)b0s)[tid]      = s0[tid];
        else if (tid < 32) ((float4*)b1s)[tid - 16] = s1[tid - 16];
        if (tid < 3) b2s[tid] = b2[3 * g + tid];
    }

    // ---- stage input tile ----
    for (int idx = tid; idx < 21 * 21; idx += 256) {
        const int r = idx / 21;
        const int c = idx - r * 21;
        int gy = by * 16 - 2 + r; gy = gy < 0 ? 0 : (gy > 255 ? 255 : gy);
        int gx = bx * 16 - 2 + c; gx = gx < 0 ? 0 : (gx > 255 ? 255 : gx);
        tile[r][c] = y[gy * 256 + gx];
    }
    __syncthreads();

    float patch[36];
#pragma unroll
    for (int i = 0; i < 6; ++i)
#pragma unroll
        for (int j = 0; j < 6; ++j)
            patch[i * 6 + j] = tile[ty + i][tx + j];

    // ---- conv1: 36 -> 64 (this group), serial fmaf order preserved ----
    float h0[64];
#pragma unroll 4
    for (int c = 0; c < 64; ++c) {
        const float4* w4 = (const float4*)(w0s + c * 36);   // 9 f4, 16B-aligned
        float acc = 0.0f;
#pragma unroll
        for (int q = 0; q < 9; ++q) {
            const float4 wv = w4[q];
            acc = fmaf(wv.x, patch[4 * q + 0], acc);
            acc = fmaf(wv.y, patch[4 * q + 1], acc);
            acc = fmaf(wv.z, patch[4 * q + 2], acc);
            acc = fmaf(wv.w, patch[4 * q + 3], acc);
        }
        acc = acc + b0s[c];
        h0[c] = fmaxf(acc, 0.0f);
    }

    // ---- conv2 (64->64) fused with conv3 (64->3), order preserved ----
    float p0 = 0.0f, p1 = 0.0f, p2 = 0.0f;
#pragma unroll 4
    for (int c = 0; c < 64; ++c) {
        const float4* w4 = (const float4*)(w1s + c * 64);   // 16 f4
        float acc = 0.0f;
#pragma unroll
        for (int q = 0; q < 16; ++q) {
            const float4 wv = w4[q];
            acc = fmaf(wv.x, h0[4 * q + 0], acc);
            acc = fmaf(wv.y, h0[4 * q + 1], acc);
            acc = fmaf(wv.z, h0[4 * q + 2], acc);
            acc = fmaf(wv.w, h0[4 * q + 3], acc);
        }
        acc = acc + b1s[c];
        acc = fmaxf(acc, 0.0f);
        p0 = fmaf(w2s[0 * 64 + c], acc, p0);
        p1 = fmaf(w2s[1 * 64 + c], acc, p1);
        p2 = fmaf(w2s[2 * 64 + c], acc, p2);
    }
    p0 = p0 + b2s[0];
    p1 = p1 + b2s[1];
    p2 = p2 + b2s[2];

    const int pix = (by * 16 + ty) * 256 + bx * 16 + tx;

    if (g == 0) {
        prm_g[0 * NPIX + pix] = p0;
        prm_g[1 * NPIX + pix] = p1;
        prm_g[2 * NPIX + pix] = p2;
    } else if (g == 1) {
        prm_g[3 * NPIX + pix] = fmaxf(xla_exp32(p0), 0.11f);
        prm_g[4 * NPIX + pix] = fmaxf(xla_exp32(p1), 0.11f);
        prm_g[5 * NPIX + pix] = fmaxf(xla_exp32(p2), 0.11f);
    } else {
        const float m  = fmaxf(fmaxf(p0, p1), p2);
        const float e0 = xla_exp32(p0 - m);
        const float e1 = xla_exp32(p1 - m);
        const float e2 = xla_exp32(p2 - m);
        const float s  = (e0 + e1) + e2;
        prm_g[6 * NPIX + pix] = e0 / s;
        prm_g[7 * NPIX + pix] = e1 / s;
        prm_g[8 * NPIX + pix] = e2 / s;
    }
}

// ===========================================================================
// Kernel B: CDF evaluation.  Grid NPIX/PPB = 2048 blocks, 256 threads.
// Thread tid evaluates point l = tid for PPB pixels (coalesced stores),
// then threads 0..PPB-1 handle the l=256 tail point.
// ===========================================================================
__global__ __launch_bounds__(256) void entropy_cdf(
    const float* __restrict__ prm_g,
    int* __restrict__ out)
{
#pragma clang fp contract(off)
    __shared__ float prm[9][PPB];

    const int base = blockIdx.x * PPB;
    const int tid  = threadIdx.x;

    for (int i = tid; i < 9 * PPB; i += 256)
        prm[i >> 5][i & 31] = prm_g[(i >> 5) * NPIX + base + (i & 31)];
    __syncthreads();

    const float CLIP = (float)(1.0 - 1e-6);

    // main: point l = tid for every pixel in the block
    {
        const int l = tid;
        const float t32 = (l == 0)
            ? (float)(-147.5 / 255.0)
            : (float)((((double)l) - 127.5) / 255.0);
#pragma unroll 4
        for (int p = 0; p < PPB; ++p) {
            const float mu0 = prm[0][p], mu1 = prm[1][p], mu2 = prm[2][p];
            const float sc0 = prm[3][p], sc1 = prm[4][p], sc2 = prm[5][p];
            const float w0  = prm[6][p], w1  = prm[7][p], w2  = prm[8][p];

            const float n0 = xla_ndtr32((t32 - mu0) / sc0);
            const float n1 = xla_ndtr32((t32 - mu1) / sc1);
            const float n2 = xla_ndtr32((t32 - mu2) / sc2);

            float cdf = fmaf(w2, n2, fmaf(w1, n1, w0 * n0));
            cdf = fminf(fmaxf(cdf, 0.0f), CLIP);

            out[(size_t)(base + p) * LPTS + l] = quantize(cdf, l);
        }
    }

    // tail: point l = 256, one pixel per thread
    if (tid < PPB) {
        const int p = tid;
        const float t32 = (float)(148.5 / 255.0);
        const float mu0 = prm[0][p], mu1 = prm[1][p], mu2 = prm[2][p];
        const float sc0 = prm[3][p], sc1 = prm[4][p], sc2 = prm[5][p];
        const float w0  = prm[6][p], w1  = prm[7][p], w2  = prm[8][p];

        const float n0 = xla_ndtr32((t32 - mu0) / sc0);
        const float n1 = xla_ndtr32((t32 - mu1) / sc1);
        const float n2 = xla_ndtr32((t32 - mu2) / sc2);

        float cdf = fmaf(w2, n2, fmaf(w1, n1, w0 * n0));
        cdf = fminf(fmaxf(cdf, 0.0f), CLIP);

        out[(size_t)(base + p) * LPTS + 256] = quantize(cdf, 256);
    }
}

// ===========================================================================
// Fallback: fused single-kernel (used only if ws_size is too small).
// ===========================================================================
__global__ __launch_bounds__(256) void entropy_fused(
    const float* __restrict__ y,
    const float* __restrict__ W0, const float* __restrict__ b0,
    const float* __restrict__ W1, const float* __restrict__ b1,
    const float* __restrict__ W2, const float* __restrict__ b2,
    int* __restrict__ out)
{
#pragma clang fp contract(off)

    __shared__ float tile[21][22];
    __shared__ float prm[9][257];

    const int bx  = blockIdx.x & 15;
    const int by  = blockIdx.x >> 4;
    const int tid = threadIdx.x;
    const int tx  = tid & 15;
    const int ty  = tid >> 4;

    for (int idx = tid; idx < 21 * 21; idx += 256) {
        const int r = idx / 21;
        const int c = idx - r * 21;
        int gy = by * 16 - 2 + r; gy = gy < 0 ? 0 : (gy > 255 ? 255 : gy);
        int gx = bx * 16 - 2 + c; gx = gx < 0 ? 0 : (gx > 255 ? 255 : gx);
        tile[r][c] = y[gy * 256 + gx];
    }
    __syncthreads();

    float patch[36];
#pragma unroll
    for (int i = 0; i < 6; ++i)
#pragma unroll
        for (int j = 0; j < 6; ++j)
            patch[i * 6 + j] = tile[ty + i][tx + j];

    for (int g = 0; g < 3; ++g) {
        float h0[64];
#pragma unroll 2
        for (int c = 0; c < 64; ++c) {
            float acc = 0.0f;
            const float* w = W0 + (g * 64 + c) * 36;
#pragma unroll
            for (int k = 0; k < 36; ++k)
                acc = fmaf(w[k], patch[k], acc);
            acc = acc + b0[g * 64 + c];
            h0[c] = fmaxf(acc, 0.0f);
        }

        float p0 = 0.0f, p1 = 0.0f, p2 = 0.0f;
#pragma unroll 2
        for (int c = 0; c < 64; ++c) {
            float acc = 0.0f;
            const float* w = W1 + (g * 64 + c) * 64;
#pragma unroll
            for (int j = 0; j < 64; ++j)
                acc = fmaf(w[j], h0[j], acc);
            acc = acc + b1[g * 64 + c];
            acc = fmaxf(acc, 0.0f);
            p0 = fmaf(W2[(3 * g + 0) * 64 + c], acc, p0);
            p1 = fmaf(W2[(3 * g + 1) * 64 + c], acc, p1);
            p2 = fmaf(W2[(3 * g + 2) * 64 + c], acc, p2);
        }
        p0 = p0 + b2[3 * g + 0];
        p1 = p1 + b2[3 * g + 1];
        p2 = p2 + b2[3 * g + 2];

        if (g == 0) {
            prm[0][tid] = p0; prm[1][tid] = p1; prm[2][tid] = p2;
        } else if (g == 1) {
            prm[3][tid] = fmaxf(xla_exp32(p0), 0.11f);
            prm[4][tid] = fmaxf(xla_exp32(p1), 0.11f);
            prm[5][tid] = fmaxf(xla_exp32(p2), 0.11f);
        } else {
            const float m  = fmaxf(fmaxf(p0, p1), p2);
            const float e0 = xla_exp32(p0 - m);
            const float e1 = xla_exp32(p1 - m);
            const float e2 = xla_exp32(p2 - m);
            const float s  = (e0 + e1) + e2;
            prm[6][tid] = e0 / s;
            prm[7][tid] = e1 / s;
            prm[8][tid] = e2 / s;
        }
    }
    __syncthreads();

    const int rowbase = (by * 16) * 256 + bx * 16;
    const float CLIP = (float)(1.0 - 1e-6);

    {
        const int l = tid;
        const float t32 = (l == 0)
            ? (float)(-147.5 / 255.0)
            : (float)((((double)l) - 127.5) / 255.0);
        for (int p = 0; p < 256; ++p) {
            const float mu0 = prm[0][p], mu1 = prm[1][p], mu2 = prm[2][p];
            const float sc0 = prm[3][p], sc1 = prm[4][p], sc2 = prm[5][p];
            const float w0  = prm[6][p], w1  = prm[7][p], w2  = prm[8][p];

            const float n0 = xla_ndtr32((t32 - mu0) / sc0);
            const float n1 = xla_ndtr32((t32 - mu1) / sc1);
            const float n2 = xla_ndtr32((t32 - mu2) / sc2);

            float cdf = fmaf(w2, n2, fmaf(w1, n1, w0 * n0));
            cdf = fminf(fmaxf(cdf, 0.0f), CLIP);

            const int pix = rowbase + (p >> 4) * 256 + (p & 15);
            out[(size_t)pix * LPTS + l] = quantize(cdf, l);
        }
    }

    {
        const int p = tid;
        const float t32 = (float)(148.5 / 255.0);
        const float mu0 = prm[0][p], mu1 = prm[1][p], mu2 = prm[2][p];
        const float sc0 = prm[3][p], sc1 = prm[4][p], sc2 = prm[5][p];
        const float w0  = prm[6][p], w1  = prm[7][p], w2  = prm[8][p];

        const float n0 = xla_ndtr32((t32 - mu0) / sc0);
        const float n1 = xla_ndtr32((t32 - mu1) / sc1);
        const float n2 = xla_ndtr32((t32 - mu2) / sc2);

        float cdf = fmaf(w2, n2, fmaf(w1, n1, w0 * n0));
        cdf = fminf(fmaxf(cdf, 0.0f), CLIP);

        const int pix = rowbase + (p >> 4) * 256 + (p & 15);
        out[(size_t)pix * LPTS + 256] = quantize(cdf, 256);
    }
}

// ===========================================================================
extern "C" void kernel_launch(void* const* d_in, const int* in_sizes, int n_in,
                              void* d_out, int out_size, void* d_ws, size_t ws_size,
                              hipStream_t stream)
{
    const float* y  = (const float*)d_in[0];
    const float* W0 = (const float*)d_in[1];
    const float* b0 = (const float*)d_in[2];
    const float* W1 = (const float*)d_in[3];
    const float* b1 = (const float*)d_in[4];
    const float* W2 = (const float*)d_in[5];
    const float* b2 = (const float*)d_in[6];

    int* out = (int*)d_out;   // 65536 * 257 int32

    const size_t need = (size_t)9 * NPIX * sizeof(float);
    if (d_ws != nullptr && ws_size >= need) {
        float* prm_g = (float*)d_ws;
        entropy_params<<<dim3(256, 3), dim3(256), 0, stream>>>(
            y, W0, b0, W1, b1, W2, b2, prm_g);
        entropy_cdf<<<dim3(NPIX / PPB), dim3(256), 0, stream>>>(prm_g, out);
    } else {
        entropy_fused<<<dim3(256), dim3(256), 0, stream>>>(
            y, W0, b0, W1, b1, W2, b2, out);
    }
}

// Round 3
// 177.706 us; speedup vs baseline: 2.3813x; 1.1391x over previous
//
#include <hip/hip_runtime.h>
#include <math.h>

#define LPTS 257
#define NPIX 65536
#define PPB  32      // pixels per block in the CDF kernel

// ===========================================================================
// XLA-CPU float32 emulation (bit-identical):
//   exp  : Eigen pexp (fmaf)
//   erf  : XLA alpha/beta rational, fmaf; final div done via the compiler's
//          own core sequence (rcp + NR + 2 fma corrections) without the
//          div_scale/div_fixup range handling (operands are tame) and
//          without the s_denorm_mode toggles.
//   z    : (t - mu)/sc with per-pixel precomputed yh = RN(1/sc) + one
//          Markstein fma-correction step == RN((t-mu)/sc)  (proven correct
//          when yh is the correctly rounded reciprocal; sc in [0.11, ~e^5]).
//   0.5  : ndtr's final 0.5*y folded into the softmax weights (exact scaling
//          => identical product roundings).
//   cast : XLA float->int16 SATURATES high; int16 ADD wraps.
// Round 15: params VGPR cap raised (no h0[64] spill), cdf made division-free.
// ===========================================================================

__device__ __forceinline__ float xla_exp32(float x)
{
#pragma clang fp contract(off)
    x = fminf(x, 88.3762626647950f);
    x = fmaxf(x, -87.3365478515625f);
    const float m = floorf(fmaf(x, 1.44269504088896341f, 0.5f));
    float r = fmaf(m, -0.693359375f, x);
    r = fmaf(m, 2.12194440e-4f, r);
    const float r2 = r * r;
    float p = 1.9875691500e-4f;
    p = fmaf(p, r, 1.3981999507e-3f);
    p = fmaf(p, r, 8.3334519073e-3f);
    p = fmaf(p, r, 4.1665795894e-2f);
    p = fmaf(p, r, 1.6666665459e-1f);
    p = fmaf(p, r, 5.0000001201e-1f);
    float y = fmaf(p, r2, r) + 1.0f;
    const int e = (int)m;
    const float s = __int_as_float((e + 127) << 23);   // 2^m
    return y * s;
}

// IEEE-identical f32 division for tame operands: this is exactly the
// arithmetic core of LLVM's amdgcn div expansion (v_rcp + NR + two fma
// corrections == div_fmas chain with scale 2^0, fixup = identity).
__device__ __forceinline__ float ieee_div(float n, float d)
{
    const float r0 = __builtin_amdgcn_rcpf(d);
    const float e  = fmaf(-d, r0, 1.0f);
    const float r1 = fmaf(e, r0, r0);
    const float q0 = n * r1;
    const float e1 = fmaf(-d, q0, n);
    const float q1 = fmaf(e1, r1, q0);
    const float e2 = fmaf(-d, q1, n);
    return fmaf(e2, r1, q1);
}

__device__ __forceinline__ float xla_erf32(float x)
{
#pragma clang fp contract(off)
    x = fminf(fmaxf(x, -4.0f), 4.0f);
    const float x2 = x * x;
    float pa = -2.72614225801306e-10f;
    pa = fmaf(pa, x2, 2.77068142495902e-08f);
    pa = fmaf(pa, x2, -2.10102402082508e-06f);
    pa = fmaf(pa, x2, -5.69250639462346e-05f);
    pa = fmaf(pa, x2, -7.34990630326855e-04f);
    pa = fmaf(pa, x2, -2.95459980854025e-03f);
    pa = fmaf(pa, x2, -1.60960333262415e-02f);
    float pb = -1.45660718464996e-05f;
    pb = fmaf(pb, x2, -2.13374055278905e-04f);
    pb = fmaf(pb, x2, -1.68282697438203e-03f);
    pb = fmaf(pb, x2, -7.37332916720468e-03f);
    pb = fmaf(pb, x2, -1.42647390514189e-02f);
    return ieee_div(x * pa, pb);
}

// erfc core for x >= 1 (rare path; wave-uniformly skipped)
__device__ __forceinline__ float xla_erfc_ge1(float x)
{
#pragma clang fp contract(off)
    const float z = xla_exp32(-(x * x));
    const float q = 1.0f / x;
    const float y2 = q * q;
    float p;
    if (x < 2.0f) {
        p = 2.326819970068386e-02f;
        p = fmaf(p, y2, -1.387039388740657e-01f);
        p = fmaf(p, y2, 3.687424674597105e-01f);
        p = fmaf(p, y2, -5.824733027278666e-01f);
        p = fmaf(p, y2, 6.210004621745983e-01f);
        p = fmaf(p, y2, -4.944515323274145e-01f);
        p = fmaf(p, y2, 3.404879937665872e-01f);
        p = fmaf(p, y2, -2.741127028184656e-01f);
        p = fmaf(p, y2, 5.638259427386472e-01f);
    } else {
        p = -1.047766399936249e+01f;
        p = fmaf(p, y2, 1.297719955372516e+01f);
        p = fmaf(p, y2, -7.495518717768503e+00f);
        p = fmaf(p, y2, 2.921019019210786e+00f);
        p = fmaf(p, y2, -1.015265279202700e+00f);
        p = fmaf(p, y2, 4.218463358204948e-01f);
        p = fmaf(p, y2, -2.820767439740514e-01f);
        p = fmaf(p, y2, 5.641895067754075e-01f);
    }
    return z * q * p;
}

// Three ndtrs at once; returns y_i (NOT halved -- the 0.5 is folded into the
// halved softmax weights).  One ballot guard for all three rare paths.
// Region logic bit-identical to the verified 3-region form:
//   aw<c    : 1+erf(w)
//   c<=aw<=1: sel(w>0, 2-e, e), e = 1-erf(aw) = 1-|erf(w)| (erf exactly odd)
//   aw>1    : erfc path, entered only if some lane needs it
__device__ __forceinline__ void xla_ndtr3_y(
    float z0, float z1, float z2, float& o0, float& o1, float& o2)
{
#pragma clang fp contract(off)
    const float c = __uint_as_float(0x3f3504f3u);   // f32(0.5*f32(sqrt(2)))
    const float w0 = z0 * c, w1 = z1 * c, w2 = z2 * c;
    const float a0 = fabsf(w0), a1 = fabsf(w1), a2 = fabsf(w2);

    const float E0 = xla_erf32(w0);
    const float E1 = xla_erf32(w1);
    const float E2 = xla_erf32(w2);

    const float m0 = 1.0f - fabsf(E0);
    const float m1 = 1.0f - fabsf(E1);
    const float m2 = 1.0f - fabsf(E2);

    float y0 = (a0 < c) ? (1.0f + E0) : ((w0 > 0.0f) ? (2.0f - m0) : m0);
    float y1 = (a1 < c) ? (1.0f + E1) : ((w1 > 0.0f) ? (2.0f - m1) : m1);
    float y2 = (a2 < c) ? (1.0f + E2) : ((w2 > 0.0f) ? (2.0f - m2) : m2);

    const float amax = fmaxf(fmaxf(a0, a1), a2);
    if (__builtin_expect(__ballot(amax > 1.0f) != 0ull, 0)) {
        {
            const float ec = xla_erfc_ge1(a0);
            const float yc = (w0 > 0.0f) ? (2.0f - ec) : ec;
            y0 = (a0 > 1.0f) ? yc : y0;
        }
        {
            const float ec = xla_erfc_ge1(a1);
            const float yc = (w1 > 0.0f) ? (2.0f - ec) : ec;
            y1 = (a1 > 1.0f) ? yc : y1;
        }
        {
            const float ec = xla_erfc_ge1(a2);
            const float yc = (w2 > 0.0f) ? (2.0f - ec) : ec;
            y2 = (a2 > 1.0f) ? yc : y2;
        }
    }
    o0 = y0; o1 = y1; o2 = y2;
}

// single-ndtr version for the fallback kernel (returns 0.5*y)
__device__ __forceinline__ float xla_ndtr32(float zf)
{
#pragma clang fp contract(off)
    const float c = __uint_as_float(0x3f3504f3u);
    const float w = zf * c;
    const float aw = fabsf(w);
    const float E = xla_erf32(w);
    const float e_mid = 1.0f - fabsf(E);
    float y = (aw < c) ? (1.0f + E)
                       : ((w > 0.0f) ? (2.0f - e_mid) : e_mid);
    if (__builtin_expect(__ballot(aw > 1.0f) != 0ull, 0)) {
        const float ec = xla_erfc_ge1(aw);
        const float yc = (w > 0.0f) ? (2.0f - ec) : ec;
        y = (aw > 1.0f) ? yc : y;
    }
    return 0.5f * y;
}

// saturating f32->i16 cast (XLA semantics), then wrapping i16 add of l
__device__ __forceinline__ int quantize(float cdf, int l)
{
    int r = (int)rintf(cdf * 65280.0f);
    r = r > 32767 ? 32767 : r;
    r = r < -32768 ? -32768 : r;
    return (int)((short)(r + l));
}

// ===========================================================================
// Kernel A: CNN -> per-pixel mixture params.  Grid (256 tiles, 3 groups).
// launch_bounds(256,2): VGPR cap 256 so h0[64] stays in registers (the 60-VGPR
// build spilled it: 51 MB scratch writes per dispatch).
// Output SoA prm_g[j*NPIX+pix]: j=0..2 mu, 3..5 sc, 6..8 yh=RN(1/sc),
// 9..11 hw=0.5*softmax_w.
// ===========================================================================
__global__ __launch_bounds__(256, 2) void entropy_params(
    const float* __restrict__ y,
    const float* __restrict__ W0, const float* __restrict__ b0,
    const float* __restrict__ W1, const float* __restrict__ b1,
    const float* __restrict__ W2, const float* __restrict__ b2,
    float* __restrict__ prm_g)
{
#pragma clang fp contract(off)
    __shared__ float tile[21][22];
    __shared__ __align__(16) float w0s[64 * 36];
    __shared__ __align__(16) float w1s[64 * 64];
    __shared__ __align__(16) float w2s[3 * 64];
    __shared__ __align__(16) float b0s[64];
    __shared__ __align__(16) float b1s[64];
    __shared__ float b2s[3];

    const int bx  = blockIdx.x & 15;
    const int by  = blockIdx.x >> 4;
    const int g   = blockIdx.y;
    const int tid = threadIdx.x;
    const int tx  = tid & 15;
    const int ty  = tid >> 4;

    {
        const float4* src = (const float4*)(W0 + g * 64 * 36);   // 576 f4
        for (int i = tid; i < 576; i += 256) ((float4*)w0s)[i] = src[i];
    }
    {
        const float4* src = (const float4*)(W1 + g * 64 * 64);   // 1024 f4
        for (int i = tid; i < 1024; i += 256) ((float4*)w1s)[i] = src[i];
    }
    {
        const float4* src = (const float4*)(W2 + g * 3 * 64);    // 48 f4
        if (tid < 48) ((float4*)w2s)[tid] = src[tid];
    }
    {
        const float4* s0 = (const float4*)(b0 + g * 64);
        const float4* s1 = (const float4*)(b1 + g * 64);
        if (tid < 16)      ((float4*)b0s)[tid]      = s0[tid];
        else if (tid < 32) ((float4*)b1s)[tid - 16] = s1[tid - 16];
        if (tid < 3) b2s[tid] = b2[3 * g + tid];
    }

    for (int idx = tid; idx < 21 * 21; idx += 256) {
        const int r = idx / 21;
        const int c = idx - r * 21;
        int gy = by * 16 - 2 + r; gy = gy < 0 ? 0 : (gy > 255 ? 255 : gy);
        int gx = bx * 16 - 2 + c; gx = gx < 0 ? 0 : (gx > 255 ? 255 : gx);
        tile[r][c] = y[gy * 256 + gx];
    }
    __syncthreads();

    float patch[36];
#pragma unroll
    for (int i = 0; i < 6; ++i)
#pragma unroll
        for (int j = 0; j < 6; ++j)
            patch[i * 6 + j] = tile[ty + i][tx + j];

    // conv1: 36 -> 64 (this group); serial fmaf order preserved
    float h0[64];
#pragma unroll 4
    for (int c = 0; c < 64; ++c) {
        const float4* w4 = (const float4*)(w0s + c * 36);
        float acc = 0.0f;
#pragma unroll
        for (int q = 0; q < 9; ++q) {
            const float4 wv = w4[q];
            acc = fmaf(wv.x, patch[4 * q + 0], acc);
            acc = fmaf(wv.y, patch[4 * q + 1], acc);
            acc = fmaf(wv.z, patch[4 * q + 2], acc);
            acc = fmaf(wv.w, patch[4 * q + 3], acc);
        }
        acc = acc + b0s[c];
        h0[c] = fmaxf(acc, 0.0f);
    }

    // conv2 (64->64) fused with conv3 (64->3); order preserved
    float p0 = 0.0f, p1 = 0.0f, p2 = 0.0f;
#pragma unroll 4
    for (int c = 0; c < 64; ++c) {
        const float4* w4 = (const float4*)(w1s + c * 64);
        float acc = 0.0f;
#pragma unroll
        for (int q = 0; q < 16; ++q) {
            const float4 wv = w4[q];
            acc = fmaf(wv.x, h0[4 * q + 0], acc);
            acc = fmaf(wv.y, h0[4 * q + 1], acc);
            acc = fmaf(wv.z, h0[4 * q + 2], acc);
            acc = fmaf(wv.w, h0[4 * q + 3], acc);
        }
        acc = acc + b1s[c];
        acc = fmaxf(acc, 0.0f);
        p0 = fmaf(w2s[0 * 64 + c], acc, p0);
        p1 = fmaf(w2s[1 * 64 + c], acc, p1);
        p2 = fmaf(w2s[2 * 64 + c], acc, p2);
    }
    p0 = p0 + b2s[0];
    p1 = p1 + b2s[1];
    p2 = p2 + b2s[2];

    const int pix = (by * 16 + ty) * 256 + bx * 16 + tx;

    if (g == 0) {
        prm_g[0 * NPIX + pix] = p0;
        prm_g[1 * NPIX + pix] = p1;
        prm_g[2 * NPIX + pix] = p2;
    } else if (g == 1) {
        const float s0 = fmaxf(xla_exp32(p0), 0.11f);
        const float s1 = fmaxf(xla_exp32(p1), 0.11f);
        const float s2 = fmaxf(xla_exp32(p2), 0.11f);
        prm_g[3 * NPIX + pix] = s0;
        prm_g[4 * NPIX + pix] = s1;
        prm_g[5 * NPIX + pix] = s2;
        prm_g[6 * NPIX + pix] = 1.0f / s0;   // RN(1/sc): true IEEE div, once
        prm_g[7 * NPIX + pix] = 1.0f / s1;
        prm_g[8 * NPIX + pix] = 1.0f / s2;
    } else {
        const float m  = fmaxf(fmaxf(p0, p1), p2);
        const float e0 = xla_exp32(p0 - m);
        const float e1 = xla_exp32(p1 - m);
        const float e2 = xla_exp32(p2 - m);
        const float s  = (e0 + e1) + e2;
        prm_g[ 9 * NPIX + pix] = 0.5f * (e0 / s);   // exact halving of w
        prm_g[10 * NPIX + pix] = 0.5f * (e1 / s);
        prm_g[11 * NPIX + pix] = 0.5f * (e2 / s);
    }
}

// ===========================================================================
// Kernel B: CDF evaluation.  Grid NPIX/PPB = 2048 blocks, 256 threads.
// Thread tid evaluates point l = tid for PPB pixels (coalesced stores),
// then threads 0..PPB-1 handle the l=256 tail point.  Division-free hot path.
// ===========================================================================
__global__ __launch_bounds__(256, 4) void entropy_cdf(
    const float* __restrict__ prm_g,
    int* __restrict__ out)
{
#pragma clang fp contract(off)
    __shared__ __align__(16) float prm[PPB][12];

    const int base = blockIdx.x * PPB;
    const int tid  = threadIdx.x;

    for (int i = tid; i < 12 * PPB; i += 256) {
        const int j = i >> 5;      // param index 0..11 (coalesced global read)
        const int p = i & 31;      // pixel
        prm[p][j] = prm_g[j * NPIX + base + p];
    }
    __syncthreads();

    const float CLIP = (float)(1.0 - 1e-6);

    // main: point l = tid for every pixel in the block
    {
        const int l = tid;
        const float t32 = (l == 0)
            ? (float)(-147.5 / 255.0)
            : (float)((((double)l) - 127.5) / 255.0);
#pragma unroll 4
        for (int p = 0; p < PPB; ++p) {
            const float4 v0 = *(const float4*)&prm[p][0];  // mu0 mu1 mu2 sc0
            const float4 v1 = *(const float4*)&prm[p][4];  // sc1 sc2 yh0 yh1
            const float4 v2 = *(const float4*)&prm[p][8];  // yh2 hw0 hw1 hw2

            // z_i = RN((t32-mu_i)/sc_i) via Markstein step with yh=RN(1/sc)
            const float x0 = t32 - v0.x;
            const float x1 = t32 - v0.y;
            const float x2 = t32 - v0.z;
            const float qa = x0 * v1.z;
            const float qb = x1 * v1.w;
            const float qc = x2 * v2.x;
            const float ra = fmaf(-v0.w, qa, x0);
            const float rb = fmaf(-v1.x, qb, x1);
            const float rc = fmaf(-v1.y, qc, x2);
            const float z0 = fmaf(ra, v1.z, qa);
            const float z1 = fmaf(rb, v1.w, qb);
            const float z2 = fmaf(rc, v2.x, qc);

            float y0, y1, y2;
            xla_ndtr3_y(z0, z1, z2, y0, y1, y2);

            float cdf = fmaf(v2.w, y2, fmaf(v2.z, y1, v2.y * y0));
            cdf = fminf(fmaxf(cdf, 0.0f), CLIP);

            out[(size_t)(base + p) * LPTS + l] = quantize(cdf, l);
        }
    }

    // tail: point l = 256, one pixel per thread
    if (tid < PPB) {
        const int p = tid;
        const float t32 = (float)(148.5 / 255.0);
        const float4 v0 = *(const float4*)&prm[p][0];
        const float4 v1 = *(const float4*)&prm[p][4];
        const float4 v2 = *(const float4*)&prm[p][8];

        const float x0 = t32 - v0.x;
        const float x1 = t32 - v0.y;
        const float x2 = t32 - v0.z;
        const float qa = x0 * v1.z;
        const float qb = x1 * v1.w;
        const float qc = x2 * v2.x;
        const float ra = fmaf(-v0.w, qa, x0);
        const float rb = fmaf(-v1.x, qb, x1);
        const float rc = fmaf(-v1.y, qc, x2);
        const float z0 = fmaf(ra, v1.z, qa);
        const float z1 = fmaf(rb, v1.w, qb);
        const float z2 = fmaf(rc, v2.x, qc);

        float y0, y1, y2;
        xla_ndtr3_y(z0, z1, z2, y0, y1, y2);

        float cdf = fmaf(v2.w, y2, fmaf(v2.z, y1, v2.y * y0));
        cdf = fminf(fmaxf(cdf, 0.0f), CLIP);

        out[(size_t)(base + p) * LPTS + 256] = quantize(cdf, 256);
    }
}

// ===========================================================================
// Fallback: fused single-kernel (used only if ws_size is too small).
// ===========================================================================
__global__ __launch_bounds__(256) void entropy_fused(
    const float* __restrict__ y,
    const float* __restrict__ W0, const float* __restrict__ b0,
    const float* __restrict__ W1, const float* __restrict__ b1,
    const float* __restrict__ W2, const float* __restrict__ b2,
    int* __restrict__ out)
{
#pragma clang fp contract(off)

    __shared__ float tile[21][22];
    __shared__ float prm[9][257];

    const int bx  = blockIdx.x & 15;
    const int by  = blockIdx.x >> 4;
    const int tid = threadIdx.x;
    const int tx  = tid & 15;
    const int ty  = tid >> 4;

    for (int idx = tid; idx < 21 * 21; idx += 256) {
        const int r = idx / 21;
        const int c = idx - r * 21;
        int gy = by * 16 - 2 + r; gy = gy < 0 ? 0 : (gy > 255 ? 255 : gy);
        int gx = bx * 16 - 2 + c; gx = gx < 0 ? 0 : (gx > 255 ? 255 : gx);
        tile[r][c] = y[gy * 256 + gx];
    }
    __syncthreads();

    float patch[36];
#pragma unroll
    for (int i = 0; i < 6; ++i)
#pragma unroll
        for (int j = 0; j < 6; ++j)
            patch[i * 6 + j] = tile[ty + i][tx + j];

    for (int g = 0; g < 3; ++g) {
        float h0[64];
#pragma unroll 2
        for (int c = 0; c < 64; ++c) {
            float acc = 0.0f;
            const float* w = W0 + (g * 64 + c) * 36;
#pragma unroll
            for (int k = 0; k < 36; ++k)
                acc = fmaf(w[k], patch[k], acc);
            acc = acc + b0[g * 64 + c];
            h0[c] = fmaxf(acc, 0.0f);
        }

        float p0 = 0.0f, p1 = 0.0f, p2 = 0.0f;
#pragma unroll 2
        for (int c = 0; c < 64; ++c) {
            float acc = 0.0f;
            const float* w = W1 + (g * 64 + c) * 64;
#pragma unroll
            for (int j = 0; j < 64; ++j)
                acc = fmaf(w[j], h0[j], acc);
            acc = acc + b1[g * 64 + c];
            acc = fmaxf(acc, 0.0f);
            p0 = fmaf(W2[(3 * g + 0) * 64 + c], acc, p0);
            p1 = fmaf(W2[(3 * g + 1) * 64 + c], acc, p1);
            p2 = fmaf(W2[(3 * g + 2) * 64 + c], acc, p2);
        }
        p0 = p0 + b2[3 * g + 0];
        p1 = p1 + b2[3 * g + 1];
        p2 = p2 + b2[3 * g + 2];

        if (g == 0) {
            prm[0][tid] = p0; prm[1][tid] = p1; prm[2][tid] = p2;
        } else if (g == 1) {
            prm[3][tid] = fmaxf(xla_exp32(p0), 0.11f);
            prm[4][tid] = fmaxf(xla_exp32(p1), 0.11f);
            prm[5][tid] = fmaxf(xla_exp32(p2), 0.11f);
        } else {
            const float m  = fmaxf(fmaxf(p0, p1), p2);
            const float e0 = xla_exp32(p0 - m);
            const float e1 = xla_exp32(p1 - m);
            const float e2 = xla_exp32(p2 - m);
            const float s  = (e0 + e1) + e2;
            prm[6][tid] = e0 / s;
            prm[7][tid] = e1 / s;
            prm[8][tid] = e2 / s;
        }
    }
    __syncthreads();

    const int rowbase = (by * 16) * 256 + bx * 16;
    const float CLIP = (float)(1.0 - 1e-6);

    {
        const int l = tid;
        const float t32 = (l == 0)
            ? (float)(-147.5 / 255.0)
            : (float)((((double)l) - 127.5) / 255.0);
        for (int p = 0; p < 256; ++p) {
            const float mu0 = prm[0][p], mu1 = prm[1][p], mu2 = prm[2][p];
            const float sc0 = prm[3][p], sc1 = prm[4][p], sc2 = prm[5][p];
            const float w0  = prm[6][p], w1  = prm[7][p], w2  = prm[8][p];

            const float n0 = xla_ndtr32((t32 - mu0) / sc0);
            const float n1 = xla_ndtr32((t32 - mu1) / sc1);
            const float n2 = xla_ndtr32((t32 - mu2) / sc2);

            float cdf = fmaf(w2, n2, fmaf(w1, n1, w0 * n0));
            cdf = fminf(fmaxf(cdf, 0.0f), CLIP);

            const int pix = rowbase + (p >> 4) * 256 + (p & 15);
            out[(size_t)pix * LPTS + l] = quantize(cdf, l);
        }
    }

    {
        const int p = tid;
        const float t32 = (float)(148.5 / 255.0);
        const float mu0 = prm[0][p], mu1 = prm[1][p], mu2 = prm[2][p];
        const float sc0 = prm[3][p], sc1 = prm[4][p], sc2 = prm[5][p];
        const float w0  = prm[6][p], w1  = prm[7][p], w2  = prm[8][p];

        const float n0 = xla_ndtr32((t32 - mu0) / sc0);
        const float n1 = xla_ndtr32((t32 - mu1) / sc1);
        const float n2 = xla_ndtr32((t32 - mu2) / sc2);

        float cdf = fmaf(w2, n2, fmaf(w1, n1, w0 * n0));
        cdf = fminf(fmaxf(cdf, 0.0f), CLIP);

        const int pix = rowbase + (p >> 4) * 256 + (p & 15);
        out[(size_t)pix * LPTS + 256] = quantize(cdf, 256);
    }
}

// ===========================================================================
extern "C" void kernel_launch(void* const* d_in, const int* in_sizes, int n_in,
                              void* d_out, int out_size, void* d_ws, size_t ws_size,
                              hipStream_t stream)
{
    const float* y  = (const float*)d_in[0];
    const float* W0 = (const float*)d_in[1];
    const float* b0 = (const float*)d_in[2];
    const float* W1 = (const float*)d_in[3];
    const float* b1 = (const float*)d_in[4];
    const float* W2 = (const float*)d_in[5];
    const float* b2 = (const float*)d_in[6];

    int* out = (int*)d_out;   // 65536 * 257 int32

    const size_t need = (size_t)12 * NPIX * sizeof(float);
    if (d_ws != nullptr && ws_size >= need) {
        float* prm_g = (float*)d_ws;
        entropy_params<<<dim3(256, 3), dim3(256), 0, stream>>>(
            y, W0, b0, W1, b1, W2, b2, prm_g);
        entropy_cdf<<<dim3(NPIX / PPB), dim3(256), 0, stream>>>(prm_g, out);
    } else {
        entropy_fused<<<dim3(256), dim3(256), 0, stream>>>(
            y, W0, b0, W1, b1, W2, b2, out);
    }
}

// Round 4
// 171.308 us; speedup vs baseline: 2.4703x; 1.0373x over previous
//
#include <hip/hip_runtime.h>
#include <math.h>

#define LPTS 257
#define NPIX 65536
#define PPB  32      // pixels per block in the CDF kernel

// ===========================================================================
// XLA-CPU float32 emulation (bit-identical):
//   exp  : Eigen pexp (fmaf)
//   erf  : XLA alpha/beta rational, fmaf; final div via the compiler's own
//          core sequence (rcp + NR + 2 fma corrections), operands tame.
//   z    : (t - mu)/sc with per-pixel precomputed yh = RN(1/sc) + one
//          Markstein fma-correction step == RN((t-mu)/sc).
//   0.5  : ndtr's final 0.5*y folded into the halved softmax weights.
//   cast : XLA float->int16 SATURATES high; int16 ADD wraps.
// Round 16:
//   - conv1 FULLY unrolled: h0[c] index now compile-time => h0 stays in
//     VGPRs (rule #20).  Round-3 counters showed 52 MB scratch writes from
//     the runtime-indexed h0 under partial unroll.
//   - entropy_cdf back to plain __launch_bounds__(256): the ",4" variant
//     compiled to VGPR_Count=16 (allocator straitjacket, 30 ms anomaly).
// ===========================================================================

__device__ __forceinline__ float xla_exp32(float x)
{
#pragma clang fp contract(off)
    x = fminf(x, 88.3762626647950f);
    x = fmaxf(x, -87.3365478515625f);
    const float m = floorf(fmaf(x, 1.44269504088896341f, 0.5f));
    float r = fmaf(m, -0.693359375f, x);
    r = fmaf(m, 2.12194440e-4f, r);
    const float r2 = r * r;
    float p = 1.9875691500e-4f;
    p = fmaf(p, r, 1.3981999507e-3f);
    p = fmaf(p, r, 8.3334519073e-3f);
    p = fmaf(p, r, 4.1665795894e-2f);
    p = fmaf(p, r, 1.6666665459e-1f);
    p = fmaf(p, r, 5.0000001201e-1f);
    float y = fmaf(p, r2, r) + 1.0f;
    const int e = (int)m;
    const float s = __int_as_float((e + 127) << 23);   // 2^m
    return y * s;
}

// IEEE-identical f32 division for tame operands (LLVM amdgcn div core:
// v_rcp + NR + two fma corrections; scale/fixup are identity here).
__device__ __forceinline__ float ieee_div(float n, float d)
{
    const float r0 = __builtin_amdgcn_rcpf(d);
    const float e  = fmaf(-d, r0, 1.0f);
    const float r1 = fmaf(e, r0, r0);
    const float q0 = n * r1;
    const float e1 = fmaf(-d, q0, n);
    const float q1 = fmaf(e1, r1, q0);
    const float e2 = fmaf(-d, q1, n);
    return fmaf(e2, r1, q1);
}

__device__ __forceinline__ float xla_erf32(float x)
{
#pragma clang fp contract(off)
    x = fminf(fmaxf(x, -4.0f), 4.0f);
    const float x2 = x * x;
    float pa = -2.72614225801306e-10f;
    pa = fmaf(pa, x2, 2.77068142495902e-08f);
    pa = fmaf(pa, x2, -2.10102402082508e-06f);
    pa = fmaf(pa, x2, -5.69250639462346e-05f);
    pa = fmaf(pa, x2, -7.34990630326855e-04f);
    pa = fmaf(pa, x2, -2.95459980854025e-03f);
    pa = fmaf(pa, x2, -1.60960333262415e-02f);
    float pb = -1.45660718464996e-05f;
    pb = fmaf(pb, x2, -2.13374055278905e-04f);
    pb = fmaf(pb, x2, -1.68282697438203e-03f);
    pb = fmaf(pb, x2, -7.37332916720468e-03f);
    pb = fmaf(pb, x2, -1.42647390514189e-02f);
    return ieee_div(x * pa, pb);
}

// erfc core for x >= 1 (rare path; wave-uniformly skipped)
__device__ __forceinline__ float xla_erfc_ge1(float x)
{
#pragma clang fp contract(off)
    const float z = xla_exp32(-(x * x));
    const float q = 1.0f / x;
    const float y2 = q * q;
    float p;
    if (x < 2.0f) {
        p = 2.326819970068386e-02f;
        p = fmaf(p, y2, -1.387039388740657e-01f);
        p = fmaf(p, y2, 3.687424674597105e-01f);
        p = fmaf(p, y2, -5.824733027278666e-01f);
        p = fmaf(p, y2, 6.210004621745983e-01f);
        p = fmaf(p, y2, -4.944515323274145e-01f);
        p = fmaf(p, y2, 3.404879937665872e-01f);
        p = fmaf(p, y2, -2.741127028184656e-01f);
        p = fmaf(p, y2, 5.638259427386472e-01f);
    } else {
        p = -1.047766399936249e+01f;
        p = fmaf(p, y2, 1.297719955372516e+01f);
        p = fmaf(p, y2, -7.495518717768503e+00f);
        p = fmaf(p, y2, 2.921019019210786e+00f);
        p = fmaf(p, y2, -1.015265279202700e+00f);
        p = fmaf(p, y2, 4.218463358204948e-01f);
        p = fmaf(p, y2, -2.820767439740514e-01f);
        p = fmaf(p, y2, 5.641895067754075e-01f);
    }
    return z * q * p;
}

// Three ndtrs at once; returns y_i (NOT halved -- 0.5 folded into weights).
// Region logic bit-identical to the verified 3-region form.
__device__ __forceinline__ void xla_ndtr3_y(
    float z0, float z1, float z2, float& o0, float& o1, float& o2)
{
#pragma clang fp contract(off)
    const float c = __uint_as_float(0x3f3504f3u);   // f32(0.5*f32(sqrt(2)))
    const float w0 = z0 * c, w1 = z1 * c, w2 = z2 * c;
    const float a0 = fabsf(w0), a1 = fabsf(w1), a2 = fabsf(w2);

    const float E0 = xla_erf32(w0);
    const float E1 = xla_erf32(w1);
    const float E2 = xla_erf32(w2);

    const float m0 = 1.0f - fabsf(E0);
    const float m1 = 1.0f - fabsf(E1);
    const float m2 = 1.0f - fabsf(E2);

    float y0 = (a0 < c) ? (1.0f + E0) : ((w0 > 0.0f) ? (2.0f - m0) : m0);
    float y1 = (a1 < c) ? (1.0f + E1) : ((w1 > 0.0f) ? (2.0f - m1) : m1);
    float y2 = (a2 < c) ? (1.0f + E2) : ((w2 > 0.0f) ? (2.0f - m2) : m2);

    const float amax = fmaxf(fmaxf(a0, a1), a2);
    if (__builtin_expect(__ballot(amax > 1.0f) != 0ull, 0)) {
        {
            const float ec = xla_erfc_ge1(a0);
            const float yc = (w0 > 0.0f) ? (2.0f - ec) : ec;
            y0 = (a0 > 1.0f) ? yc : y0;
        }
        {
            const float ec = xla_erfc_ge1(a1);
            const float yc = (w1 > 0.0f) ? (2.0f - ec) : ec;
            y1 = (a1 > 1.0f) ? yc : y1;
        }
        {
            const float ec = xla_erfc_ge1(a2);
            const float yc = (w2 > 0.0f) ? (2.0f - ec) : ec;
            y2 = (a2 > 1.0f) ? yc : y2;
        }
    }
    o0 = y0; o1 = y1; o2 = y2;
}

// single-ndtr version for the fallback kernel (returns 0.5*y)
__device__ __forceinline__ float xla_ndtr32(float zf)
{
#pragma clang fp contract(off)
    const float c = __uint_as_float(0x3f3504f3u);
    const float w = zf * c;
    const float aw = fabsf(w);
    const float E = xla_erf32(w);
    const float e_mid = 1.0f - fabsf(E);
    float y = (aw < c) ? (1.0f + E)
                       : ((w > 0.0f) ? (2.0f - e_mid) : e_mid);
    if (__builtin_expect(__ballot(aw > 1.0f) != 0ull, 0)) {
        const float ec = xla_erfc_ge1(aw);
        const float yc = (w > 0.0f) ? (2.0f - ec) : ec;
        y = (aw > 1.0f) ? yc : y;
    }
    return 0.5f * y;
}

// saturating f32->i16 cast (XLA semantics), then wrapping i16 add of l
__device__ __forceinline__ int quantize(float cdf, int l)
{
    int r = (int)rintf(cdf * 65280.0f);
    r = r > 32767 ? 32767 : r;
    r = r < -32768 ? -32768 : r;
    return (int)((short)(r + l));
}

// ===========================================================================
// Kernel A: CNN -> per-pixel mixture params.  Grid (256 tiles, 3 groups).
// conv1 FULLY unrolled so h0[] is statically indexed everywhere (registers).
// Output SoA prm_g[j*NPIX+pix]: j=0..2 mu, 3..5 sc, 6..8 yh=RN(1/sc),
// 9..11 hw=0.5*softmax_w.
// ===========================================================================
__global__ __launch_bounds__(256, 2) void entropy_params(
    const float* __restrict__ y,
    const float* __restrict__ W0, const float* __restrict__ b0,
    const float* __restrict__ W1, const float* __restrict__ b1,
    const float* __restrict__ W2, const float* __restrict__ b2,
    float* __restrict__ prm_g)
{
#pragma clang fp contract(off)
    __shared__ float tile[21][22];
    __shared__ __align__(16) float w0s[64 * 36];
    __shared__ __align__(16) float w1s[64 * 64];
    __shared__ __align__(16) float w2s[3 * 64];
    __shared__ __align__(16) float b0s[64];
    __shared__ __align__(16) float b1s[64];
    __shared__ float b2s[3];

    const int bx  = blockIdx.x & 15;
    const int by  = blockIdx.x >> 4;
    const int g   = blockIdx.y;
    const int tid = threadIdx.x;
    const int tx  = tid & 15;
    const int ty  = tid >> 4;

    {
        const float4* src = (const float4*)(W0 + g * 64 * 36);   // 576 f4
        for (int i = tid; i < 576; i += 256) ((float4*)w0s)[i] = src[i];
    }
    {
        const float4* src = (const float4*)(W1 + g * 64 * 64);   // 1024 f4
        for (int i = tid; i < 1024; i += 256) ((float4*)w1s)[i] = src[i];
    }
    {
        const float4* src = (const float4*)(W2 + g * 3 * 64);    // 48 f4
        if (tid < 48) ((float4*)w2s)[tid] = src[tid];
    }
    {
        const float4* s0 = (const float4*)(b0 + g * 64);
        const float4* s1 = (const float4*)(b1 + g * 64);
        if (tid < 16)      ((float4*)b0s)[tid]      = s0[tid];
        else if (tid < 32) ((float4*)b1s)[tid - 16] = s1[tid - 16];
        if (tid < 3) b2s[tid] = b2[3 * g + tid];
    }

    for (int idx = tid; idx < 21 * 21; idx += 256) {
        const int r = idx / 21;
        const int c = idx - r * 21;
        int gy = by * 16 - 2 + r; gy = gy < 0 ? 0 : (gy > 255 ? 255 : gy);
        int gx = bx * 16 - 2 + c; gx = gx < 0 ? 0 : (gx > 255 ? 255 : gx);
        tile[r][c] = y[gy * 256 + gx];
    }
    __syncthreads();

    float patch[36];
#pragma unroll
    for (int i = 0; i < 6; ++i)
#pragma unroll
        for (int j = 0; j < 6; ++j)
            patch[i * 6 + j] = tile[ty + i][tx + j];

    // conv1: 36 -> 64 (this group); FULL unroll => h0 statically indexed,
    // lives in VGPRs.  Serial fmaf order per channel preserved.
    float h0[64];
#pragma unroll
    for (int c = 0; c < 64; ++c) {
        const float4* w4 = (const float4*)(w0s + c * 36);
        float acc = 0.0f;
#pragma unroll
        for (int q = 0; q < 9; ++q) {
            const float4 wv = w4[q];
            acc = fmaf(wv.x, patch[4 * q + 0], acc);
            acc = fmaf(wv.y, patch[4 * q + 1], acc);
            acc = fmaf(wv.z, patch[4 * q + 2], acc);
            acc = fmaf(wv.w, patch[4 * q + 3], acc);
        }
        acc = acc + b0s[c];
        h0[c] = fmaxf(acc, 0.0f);
    }

    // conv2 (64->64) fused with conv3 (64->3); h0 reads statically indexed.
    float p0 = 0.0f, p1 = 0.0f, p2 = 0.0f;
#pragma unroll 4
    for (int c = 0; c < 64; ++c) {
        const float4* w4 = (const float4*)(w1s + c * 64);
        float acc = 0.0f;
#pragma unroll
        for (int q = 0; q < 16; ++q) {
            const float4 wv = w4[q];
            acc = fmaf(wv.x, h0[4 * q + 0], acc);
            acc = fmaf(wv.y, h0[4 * q + 1], acc);
            acc = fmaf(wv.z, h0[4 * q + 2], acc);
            acc = fmaf(wv.w, h0[4 * q + 3], acc);
        }
        acc = acc + b1s[c];
        acc = fmaxf(acc, 0.0f);
        p0 = fmaf(w2s[0 * 64 + c], acc, p0);
        p1 = fmaf(w2s[1 * 64 + c], acc, p1);
        p2 = fmaf(w2s[2 * 64 + c], acc, p2);
    }
    p0 = p0 + b2s[0];
    p1 = p1 + b2s[1];
    p2 = p2 + b2s[2];

    const int pix = (by * 16 + ty) * 256 + bx * 16 + tx;

    if (g == 0) {
        prm_g[0 * NPIX + pix] = p0;
        prm_g[1 * NPIX + pix] = p1;
        prm_g[2 * NPIX + pix] = p2;
    } else if (g == 1) {
        const float s0 = fmaxf(xla_exp32(p0), 0.11f);
        const float s1 = fmaxf(xla_exp32(p1), 0.11f);
        const float s2 = fmaxf(xla_exp32(p2), 0.11f);
        prm_g[3 * NPIX + pix] = s0;
        prm_g[4 * NPIX + pix] = s1;
        prm_g[5 * NPIX + pix] = s2;
        prm_g[6 * NPIX + pix] = 1.0f / s0;   // RN(1/sc): true IEEE div, once
        prm_g[7 * NPIX + pix] = 1.0f / s1;
        prm_g[8 * NPIX + pix] = 1.0f / s2;
    } else {
        const float m  = fmaxf(fmaxf(p0, p1), p2);
        const float e0 = xla_exp32(p0 - m);
        const float e1 = xla_exp32(p1 - m);
        const float e2 = xla_exp32(p2 - m);
        const float s  = (e0 + e1) + e2;
        prm_g[ 9 * NPIX + pix] = 0.5f * (e0 / s);   // exact halving of w
        prm_g[10 * NPIX + pix] = 0.5f * (e1 / s);
        prm_g[11 * NPIX + pix] = 0.5f * (e2 / s);
    }
}

// ===========================================================================
// Kernel B: CDF evaluation.  Grid NPIX/PPB = 2048 blocks, 256 threads.
// Thread tid evaluates point l = tid for PPB pixels (coalesced stores),
// then threads 0..PPB-1 handle the l=256 tail point.  Division-free hot path.
// Plain launch_bounds: the ",4" build compiled to VGPR=16 and starved.
// ===========================================================================
__global__ __launch_bounds__(256) void entropy_cdf(
    const float* __restrict__ prm_g,
    int* __restrict__ out)
{
#pragma clang fp contract(off)
    __shared__ __align__(16) float prm[PPB][12];

    const int base = blockIdx.x * PPB;
    const int tid  = threadIdx.x;

    for (int i = tid; i < 12 * PPB; i += 256) {
        const int j = i >> 5;      // param index 0..11 (coalesced global read)
        const int p = i & 31;      // pixel
        prm[p][j] = prm_g[j * NPIX + base + p];
    }
    __syncthreads();

    const float CLIP = (float)(1.0 - 1e-6);

    // main: point l = tid for every pixel in the block
    {
        const int l = tid;
        const float t32 = (l == 0)
            ? (float)(-147.5 / 255.0)
            : (float)((((double)l) - 127.5) / 255.0);
#pragma unroll 4
        for (int p = 0; p < PPB; ++p) {
            const float4 v0 = *(const float4*)&prm[p][0];  // mu0 mu1 mu2 sc0
            const float4 v1 = *(const float4*)&prm[p][4];  // sc1 sc2 yh0 yh1
            const float4 v2 = *(const float4*)&prm[p][8];  // yh2 hw0 hw1 hw2

            // z_i = RN((t32-mu_i)/sc_i) via Markstein step with yh=RN(1/sc)
            const float x0 = t32 - v0.x;
            const float x1 = t32 - v0.y;
            const float x2 = t32 - v0.z;
            const float qa = x0 * v1.z;
            const float qb = x1 * v1.w;
            const float qc = x2 * v2.x;
            const float ra = fmaf(-v0.w, qa, x0);
            const float rb = fmaf(-v1.x, qb, x1);
            const float rc = fmaf(-v1.y, qc, x2);
            const float z0 = fmaf(ra, v1.z, qa);
            const float z1 = fmaf(rb, v1.w, qb);
            const float z2 = fmaf(rc, v2.x, qc);

            float y0, y1, y2;
            xla_ndtr3_y(z0, z1, z2, y0, y1, y2);

            float cdf = fmaf(v2.w, y2, fmaf(v2.z, y1, v2.y * y0));
            cdf = fminf(fmaxf(cdf, 0.0f), CLIP);

            out[(size_t)(base + p) * LPTS + l] = quantize(cdf, l);
        }
    }

    // tail: point l = 256, one pixel per thread
    if (tid < PPB) {
        const int p = tid;
        const float t32 = (float)(148.5 / 255.0);
        const float4 v0 = *(const float4*)&prm[p][0];
        const float4 v1 = *(const float4*)&prm[p][4];
        const float4 v2 = *(const float4*)&prm[p][8];

        const float x0 = t32 - v0.x;
        const float x1 = t32 - v0.y;
        const float x2 = t32 - v0.z;
        const float qa = x0 * v1.z;
        const float qb = x1 * v1.w;
        const float qc = x2 * v2.x;
        const float ra = fmaf(-v0.w, qa, x0);
        const float rb = fmaf(-v1.x, qb, x1);
        const float rc = fmaf(-v1.y, qc, x2);
        const float z0 = fmaf(ra, v1.z, qa);
        const float z1 = fmaf(rb, v1.w, qb);
        const float z2 = fmaf(rc, v2.x, qc);

        float y0, y1, y2;
        xla_ndtr3_y(z0, z1, z2, y0, y1, y2);

        float cdf = fmaf(v2.w, y2, fmaf(v2.z, y1, v2.y * y0));
        cdf = fminf(fmaxf(cdf, 0.0f), CLIP);

        out[(size_t)(base + p) * LPTS + 256] = quantize(cdf, 256);
    }
}

// ===========================================================================
// Fallback: fused single-kernel (used only if ws_size is too small).
// ===========================================================================
__global__ __launch_bounds__(256) void entropy_fused(
    const float* __restrict__ y,
    const float* __restrict__ W0, const float* __restrict__ b0,
    const float* __restrict__ W1, const float* __restrict__ b1,
    const float* __restrict__ W2, const float* __restrict__ b2,
    int* __restrict__ out)
{
#pragma clang fp contract(off)

    __shared__ float tile[21][22];
    __shared__ float prm[9][257];

    const int bx  = blockIdx.x & 15;
    const int by  = blockIdx.x >> 4;
    const int tid = threadIdx.x;
    const int tx  = tid & 15;
    const int ty  = tid >> 4;

    for (int idx = tid; idx < 21 * 21; idx += 256) {
        const int r = idx / 21;
        const int c = idx - r * 21;
        int gy = by * 16 - 2 + r; gy = gy < 0 ? 0 : (gy > 255 ? 255 : gy);
        int gx = bx * 16 - 2 + c; gx = gx < 0 ? 0 : (gx > 255 ? 255 : gx);
        tile[r][c] = y[gy * 256 + gx];
    }
    __syncthreads();

    float patch[36];
#pragma unroll
    for (int i = 0; i < 6; ++i)
#pragma unroll
        for (int j = 0; j < 6; ++j)
            patch[i * 6 + j] = tile[ty + i][tx + j];

    for (int g = 0; g < 3; ++g) {
        float h0[64];
#pragma unroll
        for (int c = 0; c < 64; ++c) {
            float acc = 0.0f;
            const float* w = W0 + (g * 64 + c) * 36;
#pragma unroll
            for (int k = 0; k < 36; ++k)
                acc = fmaf(w[k], patch[k], acc);
            acc = acc + b0[g * 64 + c];
            h0[c] = fmaxf(acc, 0.0f);
        }

        float p0 = 0.0f, p1 = 0.0f, p2 = 0.0f;
#pragma unroll 2
        for (int c = 0; c < 64; ++c) {
            float acc = 0.0f;
            const float* w = W1 + (g * 64 + c) * 64;
#pragma unroll
            for (int j = 0; j < 64; ++j)
                acc = fmaf(w[j], h0[j], acc);
            acc = acc + b1[g * 64 + c];
            acc = fmaxf(acc, 0.0f);
            p0 = fmaf(W2[(3 * g + 0) * 64 + c], acc, p0);
            p1 = fmaf(W2[(3 * g + 1) * 64 + c], acc, p1);
            p2 = fmaf(W2[(3 * g + 2) * 64 + c], acc, p2);
        }
        p0 = p0 + b2[3 * g + 0];
        p1 = p1 + b2[3 * g + 1];
        p2 = p2 + b2[3 * g + 2];

        if (g == 0) {
            prm[0][tid] = p0; prm[1][tid] = p1; prm[2][tid] = p2;
        } else if (g == 1) {
            prm[3][tid] = fmaxf(xla_exp32(p0), 0.11f);
            prm[4][tid] = fmaxf(xla_exp32(p1), 0.11f);
            prm[5][tid] = fmaxf(xla_exp32(p2), 0.11f);
        } else {
            const float m  = fmaxf(fmaxf(p0, p1), p2);
            const float e0 = xla_exp32(p0 - m);
            const float e1 = xla_exp32(p1 - m);
            const float e2 = xla_exp32(p2 - m);
            const float s  = (e0 + e1) + e2;
            prm[6][tid] = e0 / s;
            prm[7][tid] = e1 / s;
            prm[8][tid] = e2 / s;
        }
    }
    __syncthreads();

    const int rowbase = (by * 16) * 256 + bx * 16;
    const float CLIP = (float)(1.0 - 1e-6);

    {
        const int l = tid;
        const float t32 = (l == 0)
            ? (float)(-147.5 / 255.0)
            : (float)((((double)l) - 127.5) / 255.0);
        for (int p = 0; p < 256; ++p) {
            const float mu0 = prm[0][p], mu1 = prm[1][p], mu2 = prm[2][p];
            const float sc0 = prm[3][p], sc1 = prm[4][p], sc2 = prm[5][p];
            const float w0  = prm[6][p], w1  = prm[7][p], w2  = prm[8][p];

            const float n0 = xla_ndtr32((t32 - mu0) / sc0);
            const float n1 = xla_ndtr32((t32 - mu1) / sc1);
            const float n2 = xla_ndtr32((t32 - mu2) / sc2);

            float cdf = fmaf(w2, n2, fmaf(w1, n1, w0 * n0));
            cdf = fminf(fmaxf(cdf, 0.0f), CLIP);

            const int pix = rowbase + (p >> 4) * 256 + (p & 15);
            out[(size_t)pix * LPTS + l] = quantize(cdf, l);
        }
    }

    {
        const int p = tid;
        const float t32 = (float)(148.5 / 255.0);
        const float mu0 = prm[0][p], mu1 = prm[1][p], mu2 = prm[2][p];
        const float sc0 = prm[3][p], sc1 = prm[4][p], sc2 = prm[5][p];
        const float w0  = prm[6][p], w1  = prm[7][p], w2  = prm[8][p];

        const float n0 = xla_ndtr32((t32 - mu0) / sc0);
        const float n1 = xla_ndtr32((t32 - mu1) / sc1);
        const float n2 = xla_ndtr32((t32 - mu2) / sc2);

        float cdf = fmaf(w2, n2, fmaf(w1, n1, w0 * n0));
        cdf = fminf(fmaxf(cdf, 0.0f), CLIP);

        const int pix = rowbase + (p >> 4) * 256 + (p & 15);
        out[(size_t)pix * LPTS + 256] = quantize(cdf, 256);
    }
}

// ===========================================================================
extern "C" void kernel_launch(void* const* d_in, const int* in_sizes, int n_in,
                              void* d_out, int out_size, void* d_ws, size_t ws_size,
                              hipStream_t stream)
{
    const float* y  = (const float*)d_in[0];
    const float* W0 = (const float*)d_in[1];
    const float* b0 = (const float*)d_in[2];
    const float* W1 = (const float*)d_in[3];
    const float* b1 = (const float*)d_in[4];
    const float* W2 = (const float*)d_in[5];
    const float* b2 = (const float*)d_in[6];

    int* out = (int*)d_out;   // 65536 * 257 int32

    const size_t need = (size_t)12 * NPIX * sizeof(float);
    if (d_ws != nullptr && ws_size >= need) {
        float* prm_g = (float*)d_ws;
        entropy_params<<<dim3(256, 3), dim3(256), 0, stream>>>(
            y, W0, b0, W1, b1, W2, b2, prm_g);
        entropy_cdf<<<dim3(NPIX / PPB), dim3(256), 0, stream>>>(prm_g, out);
    } else {
        entropy_fused<<<dim3(256), dim3(256), 0, stream>>>(
            y, W0, b0, W1, b1, W2, b2, out);
    }
}

// Round 5
// 168.131 us; speedup vs baseline: 2.5169x; 1.0189x over previous
//
#include <hip/hip_runtime.h>
#include <math.h>

#define LPTS 257
#define NPIX 65536
#define PPB  32      // pixels per block in the CDF kernel

// ===========================================================================
// XLA-CPU float32 emulation (bit-identical):
//   exp  : Eigen pexp (fmaf)
//   erf  : XLA alpha/beta rational, fmaf; final div via the compiler's own
//          core sequence (rcp + NR + 2 fma corrections), operands tame.
//   z    : (t - mu)/sc with per-pixel precomputed yh = RN(1/sc) + one
//          Markstein fma-correction step == RN((t-mu)/sc).
//   0.5  : ndtr's final 0.5*y folded into the halved softmax weights.
//   cast : XLA float->int16 SATURATES high; int16 ADD wraps.
// Round 17 (params only; cdf untouched):
//   - conv1/conv2 FUSED: rolled c1 loop computes scalar h0_c1 then scatters
//     into 64 statically-indexed conv2 accumulators (W1 staged TRANSPOSED,
//     row stride 68).  h0[64] array eliminated -> no AGPR shuffling, small
//     I$-resident loop body.  Accumulation order identical (c1 = j asc).
//   - 2 pixels/thread, 128-thread blocks, same 768-block grid (3/CU
//     balanced): each broadcast weight ds_read feeds 2 pixels -> LDS-pipe
//     instructions per pixel halved (the round-4 bottleneck).
// ===========================================================================

__device__ __forceinline__ float xla_exp32(float x)
{
#pragma clang fp contract(off)
    x = fminf(x, 88.3762626647950f);
    x = fmaxf(x, -87.3365478515625f);
    const float m = floorf(fmaf(x, 1.44269504088896341f, 0.5f));
    float r = fmaf(m, -0.693359375f, x);
    r = fmaf(m, 2.12194440e-4f, r);
    const float r2 = r * r;
    float p = 1.9875691500e-4f;
    p = fmaf(p, r, 1.3981999507e-3f);
    p = fmaf(p, r, 8.3334519073e-3f);
    p = fmaf(p, r, 4.1665795894e-2f);
    p = fmaf(p, r, 1.6666665459e-1f);
    p = fmaf(p, r, 5.0000001201e-1f);
    float y = fmaf(p, r2, r) + 1.0f;
    const int e = (int)m;
    const float s = __int_as_float((e + 127) << 23);   // 2^m
    return y * s;
}

// IEEE-identical f32 division for tame operands (LLVM amdgcn div core:
// v_rcp + NR + two fma corrections; scale/fixup are identity here).
__device__ __forceinline__ float ieee_div(float n, float d)
{
    const float r0 = __builtin_amdgcn_rcpf(d);
    const float e  = fmaf(-d, r0, 1.0f);
    const float r1 = fmaf(e, r0, r0);
    const float q0 = n * r1;
    const float e1 = fmaf(-d, q0, n);
    const float q1 = fmaf(e1, r1, q0);
    const float e2 = fmaf(-d, q1, n);
    return fmaf(e2, r1, q1);
}

__device__ __forceinline__ float xla_erf32(float x)
{
#pragma clang fp contract(off)
    x = fminf(fmaxf(x, -4.0f), 4.0f);
    const float x2 = x * x;
    float pa = -2.72614225801306e-10f;
    pa = fmaf(pa, x2, 2.77068142495902e-08f);
    pa = fmaf(pa, x2, -2.10102402082508e-06f);
    pa = fmaf(pa, x2, -5.69250639462346e-05f);
    pa = fmaf(pa, x2, -7.34990630326855e-04f);
    pa = fmaf(pa, x2, -2.95459980854025e-03f);
    pa = fmaf(pa, x2, -1.60960333262415e-02f);
    float pb = -1.45660718464996e-05f;
    pb = fmaf(pb, x2, -2.13374055278905e-04f);
    pb = fmaf(pb, x2, -1.68282697438203e-03f);
    pb = fmaf(pb, x2, -7.37332916720468e-03f);
    pb = fmaf(pb, x2, -1.42647390514189e-02f);
    return ieee_div(x * pa, pb);
}

// erfc core for x >= 1 (rare path; wave-uniformly skipped)
__device__ __forceinline__ float xla_erfc_ge1(float x)
{
#pragma clang fp contract(off)
    const float z = xla_exp32(-(x * x));
    const float q = 1.0f / x;
    const float y2 = q * q;
    float p;
    if (x < 2.0f) {
        p = 2.326819970068386e-02f;
        p = fmaf(p, y2, -1.387039388740657e-01f);
        p = fmaf(p, y2, 3.687424674597105e-01f);
        p = fmaf(p, y2, -5.824733027278666e-01f);
        p = fmaf(p, y2, 6.210004621745983e-01f);
        p = fmaf(p, y2, -4.944515323274145e-01f);
        p = fmaf(p, y2, 3.404879937665872e-01f);
        p = fmaf(p, y2, -2.741127028184656e-01f);
        p = fmaf(p, y2, 5.638259427386472e-01f);
    } else {
        p = -1.047766399936249e+01f;
        p = fmaf(p, y2, 1.297719955372516e+01f);
        p = fmaf(p, y2, -7.495518717768503e+00f);
        p = fmaf(p, y2, 2.921019019210786e+00f);
        p = fmaf(p, y2, -1.015265279202700e+00f);
        p = fmaf(p, y2, 4.218463358204948e-01f);
        p = fmaf(p, y2, -2.820767439740514e-01f);
        p = fmaf(p, y2, 5.641895067754075e-01f);
    }
    return z * q * p;
}

// Three ndtrs at once; returns y_i (NOT halved -- 0.5 folded into weights).
// Region logic bit-identical to the verified 3-region form.
__device__ __forceinline__ void xla_ndtr3_y(
    float z0, float z1, float z2, float& o0, float& o1, float& o2)
{
#pragma clang fp contract(off)
    const float c = __uint_as_float(0x3f3504f3u);   // f32(0.5*f32(sqrt(2)))
    const float w0 = z0 * c, w1 = z1 * c, w2 = z2 * c;
    const float a0 = fabsf(w0), a1 = fabsf(w1), a2 = fabsf(w2);

    const float E0 = xla_erf32(w0);
    const float E1 = xla_erf32(w1);
    const float E2 = xla_erf32(w2);

    const float m0 = 1.0f - fabsf(E0);
    const float m1 = 1.0f - fabsf(E1);
    const float m2 = 1.0f - fabsf(E2);

    float y0 = (a0 < c) ? (1.0f + E0) : ((w0 > 0.0f) ? (2.0f - m0) : m0);
    float y1 = (a1 < c) ? (1.0f + E1) : ((w1 > 0.0f) ? (2.0f - m1) : m1);
    float y2 = (a2 < c) ? (1.0f + E2) : ((w2 > 0.0f) ? (2.0f - m2) : m2);

    const float amax = fmaxf(fmaxf(a0, a1), a2);
    if (__builtin_expect(__ballot(amax > 1.0f) != 0ull, 0)) {
        {
            const float ec = xla_erfc_ge1(a0);
            const float yc = (w0 > 0.0f) ? (2.0f - ec) : ec;
            y0 = (a0 > 1.0f) ? yc : y0;
        }
        {
            const float ec = xla_erfc_ge1(a1);
            const float yc = (w1 > 0.0f) ? (2.0f - ec) : ec;
            y1 = (a1 > 1.0f) ? yc : y1;
        }
        {
            const float ec = xla_erfc_ge1(a2);
            const float yc = (w2 > 0.0f) ? (2.0f - ec) : ec;
            y2 = (a2 > 1.0f) ? yc : y2;
        }
    }
    o0 = y0; o1 = y1; o2 = y2;
}

// single-ndtr version for the fallback kernel (returns 0.5*y)
__device__ __forceinline__ float xla_ndtr32(float zf)
{
#pragma clang fp contract(off)
    const float c = __uint_as_float(0x3f3504f3u);
    const float w = zf * c;
    const float aw = fabsf(w);
    const float E = xla_erf32(w);
    const float e_mid = 1.0f - fabsf(E);
    float y = (aw < c) ? (1.0f + E)
                       : ((w > 0.0f) ? (2.0f - e_mid) : e_mid);
    if (__builtin_expect(__ballot(aw > 1.0f) != 0ull, 0)) {
        const float ec = xla_erfc_ge1(aw);
        const float yc = (w > 0.0f) ? (2.0f - ec) : ec;
        y = (aw > 1.0f) ? yc : y;
    }
    return 0.5f * y;
}

// saturating f32->i16 cast (XLA semantics), then wrapping i16 add of l
__device__ __forceinline__ int quantize(float cdf, int l)
{
    int r = (int)rintf(cdf * 65280.0f);
    r = r > 32767 ? 32767 : r;
    r = r < -32768 ? -32768 : r;
    return (int)((short)(r + l));
}

// ===========================================================================
// Kernel A: CNN -> per-pixel mixture params.  Grid (256 tiles, 3 groups),
// 128 threads, 2 pixels/thread (rows ty and ty+8 of the 16x16 tile).
// Fused conv pipeline: rolled c1 loop, scalar h0, static acc2[64] per pixel.
// Output SoA prm_g[j*NPIX+pix]: j=0..2 mu, 3..5 sc, 6..8 yh=RN(1/sc),
// 9..11 hw=0.5*softmax_w.
// ===========================================================================
#define W1T_LD 68   // transposed W1 row stride (16B-aligned, conflict-relief)

__global__ __launch_bounds__(128, 1) void entropy_params(
    const float* __restrict__ y,
    const float* __restrict__ W0, const float* __restrict__ b0,
    const float* __restrict__ W1, const float* __restrict__ b1,
    const float* __restrict__ W2, const float* __restrict__ b2,
    float* __restrict__ prm_g)
{
#pragma clang fp contract(off)
    __shared__ float tile[21][22];
    __shared__ __align__(16) float w0s[64 * 36];       //  9216 B
    __shared__ __align__(16) float w1t[64 * W1T_LD];   // 17408 B  [c1][c2]
    __shared__ __align__(16) float w2t[64 * 4];        //  1024 B  [c2][k]
    __shared__ __align__(16) float b0s[64];
    __shared__ __align__(16) float b1s[64];
    __shared__ float b2s[3];

    const int bx  = blockIdx.x & 15;
    const int by  = blockIdx.x >> 4;
    const int g   = blockIdx.y;
    const int tid = threadIdx.x;
    const int tx  = tid & 15;
    const int ty  = tid >> 4;          // 0..7

    // ---- stage W0 (group slice), coalesced float4 ----
    {
        const float4* src = (const float4*)(W0 + g * 64 * 36);   // 576 f4
        for (int i = tid; i < 576; i += 128) ((float4*)w0s)[i] = src[i];
    }
    // ---- stage W1 TRANSPOSED: w1t[c1*68 + c2] = W1[g*4096 + c2*64 + c1] ----
    {
        const float4* src = (const float4*)(W1 + g * 4096);      // 1024 f4
        for (int i4 = tid; i4 < 1024; i4 += 128) {
            const float4 v = src[i4];
            const int c2 = i4 >> 4;              // (i4*4)/64
            const int c1 = (i4 << 2) & 63;       // (i4*4)%64
            w1t[(c1 + 0) * W1T_LD + c2] = v.x;
            w1t[(c1 + 1) * W1T_LD + c2] = v.y;
            w1t[(c1 + 2) * W1T_LD + c2] = v.z;
            w1t[(c1 + 3) * W1T_LD + c2] = v.w;
        }
    }
    // ---- stage W2 transposed: w2t[c2*4 + k] ----
    if (tid < 64) {
        const int c2 = tid;
        w2t[c2 * 4 + 0] = W2[(3 * g + 0) * 64 + c2];
        w2t[c2 * 4 + 1] = W2[(3 * g + 1) * 64 + c2];
        w2t[c2 * 4 + 2] = W2[(3 * g + 2) * 64 + c2];
        w2t[c2 * 4 + 3] = 0.0f;
    }
    // ---- biases ----
    {
        const float4* s0 = (const float4*)(b0 + g * 64);
        const float4* s1 = (const float4*)(b1 + g * 64);
        if (tid < 16)      ((float4*)b0s)[tid]      = s0[tid];
        else if (tid < 32) ((float4*)b1s)[tid - 16] = s1[tid - 16];
        if (tid < 3) b2s[tid] = b2[3 * g + tid];
    }
    // ---- stage input tile (21x21 with edge clamp) ----
    for (int idx = tid; idx < 21 * 21; idx += 128) {
        const int r = idx / 21;
        const int c = idx - r * 21;
        int gy = by * 16 - 2 + r; gy = gy < 0 ? 0 : (gy > 255 ? 255 : gy);
        int gx = bx * 16 - 2 + c; gx = gx < 0 ? 0 : (gx > 255 ? 255 : gx);
        tile[r][c] = y[gy * 256 + gx];
    }
    __syncthreads();

    // ---- per-thread patches for pixels (ty, tx) and (ty+8, tx) ----
    float pA[36], pB[36];
#pragma unroll
    for (int i = 0; i < 6; ++i)
#pragma unroll
        for (int j = 0; j < 6; ++j) {
            pA[i * 6 + j] = tile[ty + i][tx + j];
            pB[i * 6 + j] = tile[ty + 8 + i][tx + j];
        }

    // ---- fused conv1+conv2: rolled c1, static acc2, scalar h0 ----
    float a2a[64], a2b[64];
#pragma unroll
    for (int j = 0; j < 64; ++j) { a2a[j] = 0.0f; a2b[j] = 0.0f; }

    for (int c1 = 0; c1 < 64; ++c1) {
        const float4* w4 = (const float4*)(w0s + c1 * 36);
        float ha = 0.0f, hb = 0.0f;
#pragma unroll
        for (int q = 0; q < 9; ++q) {
            const float4 wv = w4[q];
            ha = fmaf(wv.x, pA[4 * q + 0], ha);
            ha = fmaf(wv.y, pA[4 * q + 1], ha);
            ha = fmaf(wv.z, pA[4 * q + 2], ha);
            ha = fmaf(wv.w, pA[4 * q + 3], ha);
            hb = fmaf(wv.x, pB[4 * q + 0], hb);
            hb = fmaf(wv.y, pB[4 * q + 1], hb);
            hb = fmaf(wv.z, pB[4 * q + 2], hb);
            hb = fmaf(wv.w, pB[4 * q + 3], hb);
        }
        ha = fmaxf(ha + b0s[c1], 0.0f);
        hb = fmaxf(hb + b0s[c1], 0.0f);

        const float4* w1r = (const float4*)(w1t + c1 * W1T_LD);
#pragma unroll
        for (int qq = 0; qq < 16; ++qq) {
            const float4 wv = w1r[qq];
            a2a[4 * qq + 0] = fmaf(wv.x, ha, a2a[4 * qq + 0]);
            a2a[4 * qq + 1] = fmaf(wv.y, ha, a2a[4 * qq + 1]);
            a2a[4 * qq + 2] = fmaf(wv.z, ha, a2a[4 * qq + 2]);
            a2a[4 * qq + 3] = fmaf(wv.w, ha, a2a[4 * qq + 3]);
            a2b[4 * qq + 0] = fmaf(wv.x, hb, a2b[4 * qq + 0]);
            a2b[4 * qq + 1] = fmaf(wv.y, hb, a2b[4 * qq + 1]);
            a2b[4 * qq + 2] = fmaf(wv.z, hb, a2b[4 * qq + 2]);
            a2b[4 * qq + 3] = fmaf(wv.w, hb, a2b[4 * qq + 3]);
        }
    }

    // ---- epilogue: +b1, relu, conv3 fmafs in c2 order (identical order) ----
    float p0a = 0.0f, p1a = 0.0f, p2a = 0.0f;
    float p0b = 0.0f, p1b = 0.0f, p2b = 0.0f;
#pragma unroll
    for (int c2 = 0; c2 < 64; ++c2) {
        const float h1a = fmaxf(a2a[c2] + b1s[c2], 0.0f);
        const float h1b = fmaxf(a2b[c2] + b1s[c2], 0.0f);
        const float4 wv = *(const float4*)(w2t + c2 * 4);
        p0a = fmaf(wv.x, h1a, p0a);
        p1a = fmaf(wv.y, h1a, p1a);
        p2a = fmaf(wv.z, h1a, p2a);
        p0b = fmaf(wv.x, h1b, p0b);
        p1b = fmaf(wv.y, h1b, p1b);
        p2b = fmaf(wv.z, h1b, p2b);
    }
    p0a += b2s[0]; p1a += b2s[1]; p2a += b2s[2];
    p0b += b2s[0]; p1b += b2s[1]; p2b += b2s[2];

    const int pixA = (by * 16 + ty) * 256 + bx * 16 + tx;
    const int pixB = pixA + 8 * 256;

    if (g == 0) {
        prm_g[0 * NPIX + pixA] = p0a;
        prm_g[1 * NPIX + pixA] = p1a;
        prm_g[2 * NPIX + pixA] = p2a;
        prm_g[0 * NPIX + pixB] = p0b;
        prm_g[1 * NPIX + pixB] = p1b;
        prm_g[2 * NPIX + pixB] = p2b;
    } else if (g == 1) {
        const float s0a = fmaxf(xla_exp32(p0a), 0.11f);
        const float s1a = fmaxf(xla_exp32(p1a), 0.11f);
        const float s2a = fmaxf(xla_exp32(p2a), 0.11f);
        const float s0b = fmaxf(xla_exp32(p0b), 0.11f);
        const float s1b = fmaxf(xla_exp32(p1b), 0.11f);
        const float s2b = fmaxf(xla_exp32(p2b), 0.11f);
        prm_g[3 * NPIX + pixA] = s0a;
        prm_g[4 * NPIX + pixA] = s1a;
        prm_g[5 * NPIX + pixA] = s2a;
        prm_g[6 * NPIX + pixA] = 1.0f / s0a;   // RN(1/sc): true IEEE div
        prm_g[7 * NPIX + pixA] = 1.0f / s1a;
        prm_g[8 * NPIX + pixA] = 1.0f / s2a;
        prm_g[3 * NPIX + pixB] = s0b;
        prm_g[4 * NPIX + pixB] = s1b;
        prm_g[5 * NPIX + pixB] = s2b;
        prm_g[6 * NPIX + pixB] = 1.0f / s0b;
        prm_g[7 * NPIX + pixB] = 1.0f / s1b;
        prm_g[8 * NPIX + pixB] = 1.0f / s2b;
    } else {
        {
            const float m  = fmaxf(fmaxf(p0a, p1a), p2a);
            const float e0 = xla_exp32(p0a - m);
            const float e1 = xla_exp32(p1a - m);
            const float e2 = xla_exp32(p2a - m);
            const float s  = (e0 + e1) + e2;
            prm_g[ 9 * NPIX + pixA] = 0.5f * (e0 / s);
            prm_g[10 * NPIX + pixA] = 0.5f * (e1 / s);
            prm_g[11 * NPIX + pixA] = 0.5f * (e2 / s);
        }
        {
            const float m  = fmaxf(fmaxf(p0b, p1b), p2b);
            const float e0 = xla_exp32(p0b - m);
            const float e1 = xla_exp32(p1b - m);
            const float e2 = xla_exp32(p2b - m);
            const float s  = (e0 + e1) + e2;
            prm_g[ 9 * NPIX + pixB] = 0.5f * (e0 / s);
            prm_g[10 * NPIX + pixB] = 0.5f * (e1 / s);
            prm_g[11 * NPIX + pixB] = 0.5f * (e2 / s);
        }
    }
}

// ===========================================================================
// Kernel B: CDF evaluation.  Grid NPIX/PPB = 2048 blocks, 256 threads.
// Thread tid evaluates point l = tid for PPB pixels (coalesced stores),
// then threads 0..PPB-1 handle the l=256 tail point.  Division-free hot path.
// ===========================================================================
__global__ __launch_bounds__(256) void entropy_cdf(
    const float* __restrict__ prm_g,
    int* __restrict__ out)
{
#pragma clang fp contract(off)
    __shared__ __align__(16) float prm[PPB][12];

    const int base = blockIdx.x * PPB;
    const int tid  = threadIdx.x;

    for (int i = tid; i < 12 * PPB; i += 256) {
        const int j = i >> 5;      // param index 0..11 (coalesced global read)
        const int p = i & 31;      // pixel
        prm[p][j] = prm_g[j * NPIX + base + p];
    }
    __syncthreads();

    const float CLIP = (float)(1.0 - 1e-6);

    // main: point l = tid for every pixel in the block
    {
        const int l = tid;
        const float t32 = (l == 0)
            ? (float)(-147.5 / 255.0)
            : (float)((((double)l) - 127.5) / 255.0);
#pragma unroll 4
        for (int p = 0; p < PPB; ++p) {
            const float4 v0 = *(const float4*)&prm[p][0];  // mu0 mu1 mu2 sc0
            const float4 v1 = *(const float4*)&prm[p][4];  // sc1 sc2 yh0 yh1
            const float4 v2 = *(const float4*)&prm[p][8];  // yh2 hw0 hw1 hw2

            // z_i = RN((t32-mu_i)/sc_i) via Markstein step with yh=RN(1/sc)
            const float x0 = t32 - v0.x;
            const float x1 = t32 - v0.y;
            const float x2 = t32 - v0.z;
            const float qa = x0 * v1.z;
            const float qb = x1 * v1.w;
            const float qc = x2 * v2.x;
            const float ra = fmaf(-v0.w, qa, x0);
            const float rb = fmaf(-v1.x, qb, x1);
            const float rc = fmaf(-v1.y, qc, x2);
            const float z0 = fmaf(ra, v1.z, qa);
            const float z1 = fmaf(rb, v1.w, qb);
            const float z2 = fmaf(rc, v2.x, qc);

            float y0, y1, y2;
            xla_ndtr3_y(z0, z1, z2, y0, y1, y2);

            float cdf = fmaf(v2.w, y2, fmaf(v2.z, y1, v2.y * y0));
            cdf = fminf(fmaxf(cdf, 0.0f), CLIP);

            out[(size_t)(base + p) * LPTS + l] = quantize(cdf, l);
        }
    }

    // tail: point l = 256, one pixel per thread
    if (tid < PPB) {
        const int p = tid;
        const float t32 = (float)(148.5 / 255.0);
        const float4 v0 = *(const float4*)&prm[p][0];
        const float4 v1 = *(const float4*)&prm[p][4];
        const float4 v2 = *(const float4*)&prm[p][8];

        const float x0 = t32 - v0.x;
        const float x1 = t32 - v0.y;
        const float x2 = t32 - v0.z;
        const float qa = x0 * v1.z;
        const float qb = x1 * v1.w;
        const float qc = x2 * v2.x;
        const float ra = fmaf(-v0.w, qa, x0);
        const float rb = fmaf(-v1.x, qb, x1);
        const float rc = fmaf(-v1.y, qc, x2);
        const float z0 = fmaf(ra, v1.z, qa);
        const float z1 = fmaf(rb, v1.w, qb);
        const float z2 = fmaf(rc, v2.x, qc);

        float y0, y1, y2;
        xla_ndtr3_y(z0, z1, z2, y0, y1, y2);

        float cdf = fmaf(v2.w, y2, fmaf(v2.z, y1, v2.y * y0));
        cdf = fminf(fmaxf(cdf, 0.0f), CLIP);

        out[(size_t)(base + p) * LPTS + 256] = quantize(cdf, 256);
    }
}

// ===========================================================================
// Fallback: fused single-kernel (used only if ws_size is too small).
// ===========================================================================
__global__ __launch_bounds__(256) void entropy_fused(
    const float* __restrict__ y,
    const float* __restrict__ W0, const float* __restrict__ b0,
    const float* __restrict__ W1, const float* __restrict__ b1,
    const float* __restrict__ W2, const float* __restrict__ b2,
    int* __restrict__ out)
{
#pragma clang fp contract(off)

    __shared__ float tile[21][22];
    __shared__ float prm[9][257];

    const int bx  = blockIdx.x & 15;
    const int by  = blockIdx.x >> 4;
    const int tid = threadIdx.x;
    const int tx  = tid & 15;
    const int ty  = tid >> 4;

    for (int idx = tid; idx < 21 * 21; idx += 256) {
        const int r = idx / 21;
        const int c = idx - r * 21;
        int gy = by * 16 - 2 + r; gy = gy < 0 ? 0 : (gy > 255 ? 255 : gy);
        int gx = bx * 16 - 2 + c; gx = gx < 0 ? 0 : (gx > 255 ? 255 : gx);
        tile[r][c] = y[gy * 256 + gx];
    }
    __syncthreads();

    float patch[36];
#pragma unroll
    for (int i = 0; i < 6; ++i)
#pragma unroll
        for (int j = 0; j < 6; ++j)
            patch[i * 6 + j] = tile[ty + i][tx + j];

    for (int g = 0; g < 3; ++g) {
        float h0[64];
#pragma unroll
        for (int c = 0; c < 64; ++c) {
            float acc = 0.0f;
            const float* w = W0 + (g * 64 + c) * 36;
#pragma unroll
            for (int k = 0; k < 36; ++k)
                acc = fmaf(w[k], patch[k], acc);
            acc = acc + b0[g * 64 + c];
            h0[c] = fmaxf(acc, 0.0f);
        }

        float p0 = 0.0f, p1 = 0.0f, p2 = 0.0f;
#pragma unroll 2
        for (int c = 0; c < 64; ++c) {
            float acc = 0.0f;
            const float* w = W1 + (g * 64 + c) * 64;
#pragma unroll
            for (int j = 0; j < 64; ++j)
                acc = fmaf(w[j], h0[j], acc);
            acc = acc + b1[g * 64 + c];
            acc = fmaxf(acc, 0.0f);
            p0 = fmaf(W2[(3 * g + 0) * 64 + c], acc, p0);
            p1 = fmaf(W2[(3 * g + 1) * 64 + c], acc, p1);
            p2 = fmaf(W2[(3 * g + 2) * 64 + c], acc, p2);
        }
        p0 = p0 + b2[3 * g + 0];
        p1 = p1 + b2[3 * g + 1];
        p2 = p2 + b2[3 * g + 2];

        if (g == 0) {
            prm[0][tid] = p0; prm[1][tid] = p1; prm[2][tid] = p2;
        } else if (g == 1) {
            prm[3][tid] = fmaxf(xla_exp32(p0), 0.11f);
            prm[4][tid] = fmaxf(xla_exp32(p1), 0.11f);
            prm[5][tid] = fmaxf(xla_exp32(p2), 0.11f);
        } else {
            const float m  = fmaxf(fmaxf(p0, p1), p2);
            const float e0 = xla_exp32(p0 - m);
            const float e1 = xla_exp32(p1 - m);
            const float e2 = xla_exp32(p2 - m);
            const float s  = (e0 + e1) + e2;
            prm[6][tid] = e0 / s;
            prm[7][tid] = e1 / s;
            prm[8][tid] = e2 / s;
        }
    }
    __syncthreads();

    const int rowbase = (by * 16) * 256 + bx * 16;
    const float CLIP = (float)(1.0 - 1e-6);

    {
        const int l = tid;
        const float t32 = (l == 0)
            ? (float)(-147.5 / 255.0)
            : (float)((((double)l) - 127.5) / 255.0);
        for (int p = 0; p < 256; ++p) {
            const float mu0 = prm[0][p], mu1 = prm[1][p], mu2 = prm[2][p];
            const float sc0 = prm[3][p], sc1 = prm[4][p], sc2 = prm[5][p];
            const float w0  = prm[6][p], w1  = prm[7][p], w2  = prm[8][p];

            const float n0 = xla_ndtr32((t32 - mu0) / sc0);
            const float n1 = xla_ndtr32((t32 - mu1) / sc1);
            const float n2 = xla_ndtr32((t32 - mu2) / sc2);

            float cdf = fmaf(w2, n2, fmaf(w1, n1, w0 * n0));
            cdf = fminf(fmaxf(cdf, 0.0f), CLIP);

            const int pix = rowbase + (p >> 4) * 256 + (p & 15);
            out[(size_t)pix * LPTS + l] = quantize(cdf, l);
        }
    }

    {
        const int p = tid;
        const float t32 = (float)(148.5 / 255.0);
        const float mu0 = prm[0][p], mu1 = prm[1][p], mu2 = prm[2][p];
        const float sc0 = prm[3][p], sc1 = prm[4][p], sc2 = prm[5][p];
        const float w0  = prm[6][p], w1  = prm[7][p], w2  = prm[8][p];

        const float n0 = xla_ndtr32((t32 - mu0) / sc0);
        const float n1 = xla_ndtr32((t32 - mu1) / sc1);
        const float n2 = xla_ndtr32((t32 - mu2) / sc2);

        float cdf = fmaf(w2, n2, fmaf(w1, n1, w0 * n0));
        cdf = fminf(fmaxf(cdf, 0.0f), CLIP);

        const int pix = rowbase + (p >> 4) * 256 + (p & 15);
        out[(size_t)pix * LPTS + 256] = quantize(cdf, 256);
    }
}

// ===========================================================================
extern "C" void kernel_launch(void* const* d_in, const int* in_sizes, int n_in,
                              void* d_out, int out_size, void* d_ws, size_t ws_size,
                              hipStream_t stream)
{
    const float* y  = (const float*)d_in[0];
    const float* W0 = (const float*)d_in[1];
    const float* b0 = (const float*)d_in[2];
    const float* W1 = (const float*)d_in[3];
    const float* b1 = (const float*)d_in[4];
    const float* W2 = (const float*)d_in[5];
    const float* b2 = (const float*)d_in[6];

    int* out = (int*)d_out;   // 65536 * 257 int32

    const size_t need = (size_t)12 * NPIX * sizeof(float);
    if (d_ws != nullptr && ws_size >= need) {
        float* prm_g = (float*)d_ws;
        entropy_params<<<dim3(256, 3), dim3(128), 0, stream>>>(
            y, W0, b0, W1, b1, W2, b2, prm_g);
        entropy_cdf<<<dim3(NPIX / PPB), dim3(256), 0, stream>>>(prm_g, out);
    } else {
        entropy_fused<<<dim3(256), dim3(256), 0, stream>>>(
            y, W0, b0, W1, b1, W2, b2, out);
    }
}